// Round 4
// baseline (4029.411 us; speedup 1.0000x reference)
//
#include <hip/hip_runtime.h>
#include <hip/hip_bf16.h>

#define EPS 1e-5f
typedef unsigned short bfr;   // raw bf16 bits
typedef unsigned short hfr;   // raw f16 bits

static inline int cdiv(int a, int b){ return (a + b - 1) / b; }

__device__ __forceinline__ float bf2f(bfr u){ return __uint_as_float((unsigned)u << 16); }
__device__ __forceinline__ bfr f2bf(float f){
  unsigned u = __float_as_uint(f);
  u += 0x7fffu + ((u >> 16) & 1u);   // round-to-nearest-even
  return (bfr)(u >> 16);
}
__device__ __forceinline__ unsigned pack2bf(float a, float b){
  return (unsigned)f2bf(a) | ((unsigned)f2bf(b) << 16);
}
// ---- f16 storage converters (8x finer mantissa than bf16, same 2 bytes) ----
__device__ __forceinline__ float h2f(hfr u){ _Float16 h; __builtin_memcpy(&h, &u, 2); return (float)h; }
__device__ __forceinline__ hfr f2h(float f){ _Float16 h = (_Float16)f; hfr u; __builtin_memcpy(&u, &h, 2); return u; }
__device__ __forceinline__ unsigned pack2h(float a, float b){
  return (unsigned)f2h(a) | ((unsigned)f2h(b) << 16);
}
// two relu(p+q) from packed f16 words
__device__ __forceinline__ void up2h(unsigned p, unsigned q, float& a, float& b){
  a = fmaxf(h2f((hfr)(p & 0xffff)) + h2f((hfr)(q & 0xffff)), 0.f);
  b = fmaxf(h2f((hfr)(p >> 16))    + h2f((hfr)(q >> 16)),    0.f);
}

// ---------------- dtype detection (bf16 vs f32 inputs) ----------------
__global__ __launch_bounds__(256) void detect_kernel(const bfr* __restrict__ xr, int nwords, int* __restrict__ flag){
  int i = threadIdx.x;
  int bad = 0;
  if (i < nwords){
    bfr lo = xr[2 * i];            // low half of word i
    int e = (lo >> 7) & 0xFF;
    bool plausible = ((lo & 0x7FFF) == 0) || (e >= 97 && e <= 157);
    bad = plausible ? 0 : 1;
  }
  __shared__ int s[256];
  s[threadIdx.x] = bad; __syncthreads();
  for (int st = 128; st; st >>= 1){
    if (threadIdx.x < st) s[threadIdx.x] += s[threadIdx.x + st];
    __syncthreads();
  }
  if (threadIdx.x == 0) *flag = (s[0] > 32) ? 1 : 0;   // 1 => inputs are f32
}

// ---------------- batched adaptive convert: all float tensors -> f32 ws ----------------
#define NPAR 31
struct ParamPtrs { const void* p[NPAR]; };
struct ParamOfs  { int off[NPAR + 1]; };

__global__ __launch_bounds__(256) void acvt_batch_kernel(ParamPtrs pp, ParamOfs po,
                                                         float* __restrict__ out, int total,
                                                         const int* __restrict__ flag){
  int g = blockIdx.x * 256 + threadIdx.x;
  if (g >= total) return;
  int isf = *flag;
  int t = 0;
  while (po.off[t + 1] <= g) ++t;
  int i = g - po.off[t];
  out[g] = isf ? ((const float*)pp.p[t])[i] : bf2f(((const bfr*)pp.p[t])[i]);
}

// ---------------- small utility kernels ----------------
__global__ __launch_bounds__(256) void deg_kernel(const int* __restrict__ dst, int* __restrict__ deg, int E){
  int e = blockIdx.x * 256 + threadIdx.x;
  if (e < E) atomicAdd(&deg[dst[e]], 1);
}

// Wfull [2d,64] f32 -> Wt = top-bot, Wq = bot
__global__ __launch_bounds__(256) void prep_pq_kernel(const float* __restrict__ W, float* __restrict__ Wt,
                                                      float* __restrict__ Wq, int d){
  int i = blockIdx.x * 256 + threadIdx.x;
  if (i < d * 64){ Wt[i] = W[i] - W[d * 64 + i]; Wq[i] = W[d * 64 + i]; }
}

// ---------------- generic row-per-thread GEMM: out = [relu](A @ W + bias) ----------------
// AHF: A is f16 storage; OHF: out f16 storage (else f32)
template<int NOUT, bool AHF, bool OHF>
__global__ __launch_bounds__(256) void gemm_kernel(const void* __restrict__ Av, int lda,
                                                   const float* __restrict__ W, int ldw,
                                                   const float* __restrict__ bias,
                                                   void* __restrict__ Ov, int ldo,
                                                   int nrows, int K, int relu){
  __shared__ float Ws[64 * NOUT];
  const int ct = blockIdx.y * NOUT;
  const int row = blockIdx.x * 256 + threadIdx.x;
  float acc[NOUT];
#pragma unroll
  for (int c = 0; c < NOUT; ++c) acc[c] = 0.f;
  const hfr* Ah = (const hfr*)Av;
  const float* Af = (const float*)Av;
  for (int k0 = 0; k0 < K; k0 += 64){
    int kc = min(64, K - k0);
    int tot = kc * NOUT;
    for (int i = threadIdx.x; i < tot; i += 256){
      int kk = i / NOUT, cc = i - kk * NOUT;
      Ws[i] = W[(size_t)(k0 + kk) * ldw + ct + cc];
    }
    __syncthreads();
    if (row < nrows){
      const size_t basei = (size_t)row * lda + k0;
      for (int k = 0; k < kc; ++k){
        float a = AHF ? h2f(Ah[basei + k]) : Af[basei + k];
#pragma unroll
        for (int c = 0; c < NOUT; ++c) acc[c] += a * Ws[k * NOUT + c];
      }
    }
    __syncthreads();
  }
  if (row >= nrows) return;
#pragma unroll
  for (int c = 0; c < NOUT; ++c){
    float v = acc[c] + bias[ct + c];
    acc[c] = relu ? fmaxf(v, 0.f) : v;
  }
  if (OHF){
    unsigned p[NOUT / 2];
#pragma unroll
    for (int c = 0; c < NOUT; c += 2) p[c / 2] = pack2h(acc[c], acc[c + 1]);
    uint4* op = (uint4*)((hfr*)Ov + (size_t)row * ldo + ct);
#pragma unroll
    for (int i = 0; i < NOUT / 8; ++i) op[i] = make_uint4(p[4*i], p[4*i+1], p[4*i+2], p[4*i+3]);
  } else {
    float4* op = (float4*)((float*)Ov + (size_t)row * ldo + ct);
#pragma unroll
    for (int i = 0; i < NOUT / 4; ++i) op[i] = make_float4(acc[4*i], acc[4*i+1], acc[4*i+2], acc[4*i+3]);
  }
}

// ---------------- edge pass A: BN1 stats of h1 = relu(P[dst]+Q[src]), P/Q f16 ----------------
__global__ __launch_bounds__(256) void passA_kernel(const hfr* __restrict__ P, const hfr* __restrict__ Q,
                                                    const int* __restrict__ src, const int* __restrict__ dst,
                                                    float* __restrict__ stats, int E){
  const int c = threadIdx.x & 63, j = threadIdx.x >> 6;
  float sum = 0.f, sq = 0.f;
  for (int e = blockIdx.x * 4 + j; e < E; e += gridDim.x * 4){
    float v = h2f(P[(size_t)dst[e] * 64 + c]) + h2f(Q[(size_t)src[e] * 64 + c]);
    v = fmaxf(v, 0.f);
    sum += v; sq += v * v;
  }
  __shared__ float ls[256], lq[256];
  ls[threadIdx.x] = sum; lq[threadIdx.x] = sq;
  __syncthreads();
  if (threadIdx.x < 64){
    float s = ls[c] + ls[64 + c] + ls[128 + c] + ls[192 + c];
    float q = lq[c] + lq[64 + c] + lq[128 + c] + lq[192 + c];
    atomicAdd(&stats[c], s);
    atomicAdd(&stats[64 + c], q);
  }
}

// ---------------- fold BN(stats,g,be) into next Lin ----------------
__global__ __launch_bounds__(256) void fold_kernel(const float* __restrict__ stats, float cntInv,
                                                   const float* __restrict__ g, const float* __restrict__ be,
                                                   const float* __restrict__ Wn, const float* __restrict__ bn,
                                                   float* __restrict__ Wo, float* __restrict__ bo, int K, int C){
  __shared__ float a[256], bb[256];
  for (int k = threadIdx.x; k < K; k += 256){
    float mu = stats[k] * cntInv;
    float var = stats[K + k] * cntInv - mu * mu;
    float ai = g[k] * rsqrtf(var + EPS);
    a[k] = ai; bb[k] = be[k] - ai * mu;
  }
  __syncthreads();
  int tot = K * C;
  for (int i = threadIdx.x; i < tot; i += 256) Wo[i] = a[i / C] * Wn[i];
  for (int c = threadIdx.x; c < C; c += 256){
    float s = bn[c];
    for (int k = 0; k < K; ++k) s += bb[k] * Wn[(size_t)k * C + c];
    bo[c] = s;
  }
}

__global__ void bncoef_kernel(const float* __restrict__ stats, float cntInv,
                              const float* __restrict__ g, const float* __restrict__ be,
                              float* __restrict__ a, float* __restrict__ b, int C){
  int c = threadIdx.x;
  if (c < C){
    float mu = stats[c] * cntInv;
    float var = stats[C + c] * cntInv - mu * mu;
    float ai = g[c] * rsqrtf(var + EPS);
    a[c] = ai; b[c] = be[c] - ai * mu;
  }
}

// ---------------- FUSED pass B+C: per edge compute relu2 in regs, stats + scatter-max ----------------
__global__ __launch_bounds__(256) void passBC_kernel(const hfr* __restrict__ P, const hfr* __restrict__ Q,
                                                     const int* __restrict__ src, const int* __restrict__ dst,
                                                     const float* __restrict__ W2, const float* __restrict__ b2,
                                                     float* __restrict__ agg, float* __restrict__ stats, int E){
  __shared__ float Ws[64 * 64];
  __shared__ float bs[64];
  __shared__ float ls[256], lq[256];
  for (int i = threadIdx.x; i < 64 * 64; i += 256) Ws[i] = W2[i];
  if (threadIdx.x < 64) bs[threadIdx.x] = b2[threadIdx.x];
  __syncthreads();
  const int e = blockIdx.x * 256 + threadIdx.x;
  const bool act = e < E;
  float acc[64];
#pragma unroll
  for (int c = 0; c < 64; ++c) acc[c] = bs[c];
  int de = 0;
  if (act){
    de = dst[e];
    const uint4* Pp = (const uint4*)(P + (size_t)de * 64);
    const uint4* Qp = (const uint4*)(Q + (size_t)src[e] * 64);
    for (int k0 = 0; k0 < 8; ++k0){          // 8 f16 per uint4, 8 uint4 per row
      uint4 pu = Pp[k0], qu = Qp[k0];
      float h[8];
      up2h(pu.x, qu.x, h[0], h[1]);
      up2h(pu.y, qu.y, h[2], h[3]);
      up2h(pu.z, qu.z, h[4], h[5]);
      up2h(pu.w, qu.w, h[6], h[7]);
#pragma unroll
      for (int k = 0; k < 8; ++k){
        const float* wr = Ws + (k0 * 8 + k) * 64;
        float hk = h[k];
#pragma unroll
        for (int c4 = 0; c4 < 16; ++c4){
          float4 w = *(const float4*)(wr + 4 * c4);
          acc[4*c4+0] += hk * w.x;
          acc[4*c4+1] += hk * w.y;
          acc[4*c4+2] += hk * w.z;
          acc[4*c4+3] += hk * w.w;
        }
      }
    }
  }
  // relu + per-wave butterfly stats (all 64 lanes participate; inactive contribute 0)
  const int lane = threadIdx.x & 63;
  float myS = 0.f, myQ = 0.f;
#pragma unroll
  for (int c = 0; c < 64; ++c){
    float v = act ? fmaxf(acc[c], 0.f) : 0.f;
    acc[c] = v;
    float s = v, q = v * v;
#pragma unroll
    for (int m = 1; m < 64; m <<= 1){
      s += __shfl_xor(s, m, 64);
      q += __shfl_xor(q, m, 64);
    }
    if (lane == c){ myS = s; myQ = q; }
  }
  ls[threadIdx.x] = myS; lq[threadIdx.x] = myQ;
  __syncthreads();
  if (threadIdx.x < 64){
    atomicAdd(&stats[threadIdx.x],      ls[threadIdx.x] + ls[64 + threadIdx.x] + ls[128 + threadIdx.x] + ls[192 + threadIdx.x]);
    atomicAdd(&stats[64 + threadIdx.x], lq[threadIdx.x] + lq[64 + threadIdx.x] + lq[128 + threadIdx.x] + lq[192 + threadIdx.x]);
  }
  if (act){
    float* ap = agg + (size_t)de * 64;
#pragma unroll
    for (int c = 0; c < 64; ++c){
      float v = acc[c];
      if (v > 0.f && v > ap[c])            // loser-skip: agg only grows, racy read is safe
        atomicMax((unsigned*)&ap[c], __float_as_uint(v));
    }
  }
}

// x_next = deg>0 ? a*max + b : 0, f16 into xcat column slice
__global__ __launch_bounds__(256) void fixup_kernel(const float* __restrict__ agg, const int* __restrict__ deg,
                                                    const float* __restrict__ a, const float* __restrict__ b,
                                                    hfr* __restrict__ xout, int ldx, int N){
  int t = blockIdx.x * 256 + threadIdx.x;
  if (t >= N * 64) return;
  int n = t >> 6, c = t & 63;
  float v = 0.f;
  if (deg[n] > 0) v = a[c] * agg[t] + b[c];
  xout[(size_t)n * ldx + c] = f2h(v);
}

// ---------------- node BN stats over f16 activations ----------------
template<int C>
__global__ __launch_bounds__(256) void statsN_kernel(const hfr* __restrict__ u, float* __restrict__ stats, int N){
  constexpr int RP = 256 / C;
  const int c = threadIdx.x % C, j = threadIdx.x / C;
  float sum = 0.f, sq = 0.f;
  for (int r = blockIdx.x * RP + j; r < N; r += gridDim.x * RP){
    float v = h2f(u[(size_t)r * C + c]);
    sum += v; sq += v * v;
  }
  __shared__ float ls[256], lq[256];
  ls[threadIdx.x] = sum; lq[threadIdx.x] = sq;
  __syncthreads();
  if (threadIdx.x < C){
    float s = 0.f, q = 0.f;
#pragma unroll
    for (int jj = 0; jj < RP; ++jj){ s += ls[jj * C + c]; q += lq[jj * C + c]; }
    atomicAdd(&stats[c], s); atomicAdd(&stats[C + c], q);
  }
}

// ---------------- head: logits + log_softmax, dtype-adaptive store ----------------
__global__ __launch_bounds__(256) void head_kernel(const hfr* __restrict__ u2,
                                                   const float* __restrict__ Wo, const float* __restrict__ bo,
                                                   void* __restrict__ out, int N, const int* __restrict__ flag){
  __shared__ float Ws[32 * 24];
  __shared__ float bs[24];
  for (int i = threadIdx.x; i < 32 * 24; i += 256) Ws[i] = Wo[i];
  if (threadIdx.x < 24) bs[threadIdx.x] = bo[threadIdx.x];
  __syncthreads();
  int r = blockIdx.x * 256 + threadIdx.x;
  if (r >= N) return;
  int isf = *flag;
  float l[24];
#pragma unroll
  for (int c = 0; c < 24; ++c) l[c] = bs[c];
  const hfr* up = u2 + (size_t)r * 32;
#pragma unroll
  for (int k = 0; k < 32; ++k){
    float v = h2f(up[k]);
#pragma unroll
    for (int c = 0; c < 24; ++c) l[c] += v * Ws[k * 24 + c];
  }
  float m = l[0];
#pragma unroll
  for (int c = 1; c < 24; ++c) m = fmaxf(m, l[c]);
  float s = 0.f;
#pragma unroll
  for (int c = 0; c < 24; ++c) s += expf(l[c] - m);
  float lse = m + logf(s);
  if (isf){
    float4* op = (float4*)((float*)out + (size_t)r * 24);
#pragma unroll
    for (int i = 0; i < 6; ++i)
      op[i] = make_float4(l[4*i] - lse, l[4*i+1] - lse, l[4*i+2] - lse, l[4*i+3] - lse);
  } else {
    unsigned p[12];
#pragma unroll
    for (int c = 0; c < 24; c += 2) p[c / 2] = pack2bf(l[c] - lse, l[c + 1] - lse);
    uint4* op = (uint4*)((bfr*)out + (size_t)r * 24);
#pragma unroll
    for (int i = 0; i < 3; ++i) op[i] = make_uint4(p[4*i], p[4*i+1], p[4*i+2], p[4*i+3]);
  }
}

// ---------------- host ----------------
// Footprint ~47 MB (proved safe in round 3). All 2-byte intermediates are f16
// (8x finer rounding than bf16 at identical size). Aliases disjoint in time:
// u_l over P+Q+agg (dead after conv loop); u1/u2 over xcat (dead after lin1).
extern "C" void kernel_launch(void* const* d_in, const int* in_sizes, int n_in,
                              void* d_out, int out_size, void* d_ws, size_t ws_size,
                              hipStream_t stream){
  const int N = in_sizes[0] / 6;
  const int E = in_sizes[31] / 2;
  const int* edge = (const int*)d_in[31];
  const int* src = edge;
  const int* dst = edge + E;

  size_t off = 0; char* basep = (char*)d_ws;
  auto alloc = [&](size_t bytes) -> void* {
    void* p = basep + off;
    off = (off + bytes + 255) & ~(size_t)255;
    return p;
  };
  // small stuff first
  float* Wt   = (float*)alloc(64 * 64 * 4);
  float* Wq   = (float*)alloc(64 * 64 * 4);
  float* W2   = (float*)alloc(64 * 64 * 4);
  float* b2   = (float*)alloc(64 * 4);
  float* Wm1F = (float*)alloc(256 * 64 * 4);
  float* bm1F = (float*)alloc(64 * 4);
  float* Wm2F = (float*)alloc(64 * 32 * 4);
  float* bm2F = (float*)alloc(32 * 4);
  float* WoF  = (float*)alloc(32 * 24 * 4);
  float* boF  = (float*)alloc(24 * 4);
  float* zer  = (float*)alloc(64 * 4);
  float* stE  = (float*)alloc(128 * 4);
  float* stE2 = (float*)alloc(128 * 4);
  float* stN  = (float*)alloc(512 * 4);
  float* aC   = (float*)alloc(64 * 4);
  float* bC   = (float*)alloc(64 * 4);
  int*   flag = (int*)  alloc(4);
  int*   deg  = (int*)  alloc((size_t)N * 4);

  // f32 staging of all float inputs (params 1..30 then x as slot 30)
  ParamPtrs pp; ParamOfs po;
  int hoff[32]; int total = 0;
  for (int s = 0; s < NPAR; ++s){
    int idx = (s < 30) ? (s + 1) : 0;
    pp.p[s] = d_in[idx];
    po.off[s] = total;
    hoff[idx] = total;
    total += in_sizes[idx];
  }
  po.off[NPAR] = total;
  float* pf = (float*)alloc((size_t)total * 4);

  // big buffers: P,Q,agg contiguous (u_l alias needs 25.6MB), then xcat
  hfr*   P    = (hfr*)  alloc((size_t)N * 64 * 2);    // 6.4 MB
  hfr*   Qb   = (hfr*)  alloc((size_t)N * 64 * 2);    // 6.4 MB
  float* agg  = (float*)alloc((size_t)N * 64 * 4);    // 12.8 MB
  hfr*   xcat = (hfr*)  alloc((size_t)N * 192 * 2);   // 19.2 MB
  // aliases (disjoint lifetimes)
  hfr* u_l = (hfr*)P;                 // [N,256] f16 = 25.6 MB over P+Q+agg
  hfr* u1  = xcat;                    // [N,64]  f16 = 6.4 MB
  hfr* u2  = xcat + (size_t)N * 64;   // [N,32]  f16 = 3.2 MB
  (void)ws_size; (void)n_in; (void)out_size;

  dim3 B(256);
  detect_kernel<<<1, B, 0, stream>>>((const bfr*)d_in[0], 256, flag);
  acvt_batch_kernel<<<cdiv(total, 256), B, 0, stream>>>(pp, po, pf, total, flag);

  hipMemsetAsync(deg, 0, (size_t)N * 4, stream);
  hipMemsetAsync(zer, 0, 64 * 4, stream);
  deg_kernel<<<cdiv(E, 256), B, 0, stream>>>(dst, deg, E);

  const int NB = cdiv(N, 256);
  for (int k = 0; k < 3; ++k){
    const float *Wa_k, *ba_k, *ga_k, *bea_k, *Wb_k, *bb_k, *gb_k, *beb_k;
    int d;
    if (k == 0){
      Wa_k = pf + hoff[1]; ba_k = pf + hoff[2]; ga_k = pf + hoff[3]; bea_k = pf + hoff[4];
      Wb_k = pf + hoff[5]; bb_k = pf + hoff[6]; gb_k = pf + hoff[7]; beb_k = pf + hoff[8];
      d = 6;
    } else {
      int kk = k - 1;
      Wa_k = pf + hoff[9]  + (size_t)kk * 128 * 64;
      ba_k = pf + hoff[10] + kk * 64;
      ga_k = pf + hoff[11] + kk * 64;
      bea_k= pf + hoff[12] + kk * 64;
      Wb_k = pf + hoff[13] + (size_t)kk * 64 * 64;
      bb_k = pf + hoff[14] + kk * 64;
      gb_k = pf + hoff[15] + kk * 64;
      beb_k= pf + hoff[16] + kk * 64;
      d = 64;
    }
    prep_pq_kernel<<<cdiv(d * 64, 256), B, 0, stream>>>(Wa_k, Wt, Wq, d);
    // P = X@(Wtop-Wbot)+ba ; Q = X@Wbot   (f16 out)
    if (k == 0){
      gemm_kernel<64, false, true><<<dim3(NB, 1), B, 0, stream>>>(pf + hoff[0], 6, Wt, 64, ba_k, P,  64, N, 6, 0);
      gemm_kernel<64, false, true><<<dim3(NB, 1), B, 0, stream>>>(pf + hoff[0], 6, Wq, 64, zer,  Qb, 64, N, 6, 0);
    } else {
      const hfr* Ain = xcat + (size_t)(k - 1) * 64;
      gemm_kernel<64, true, true><<<dim3(NB, 1), B, 0, stream>>>(Ain, 192, Wt, 64, ba_k, P,  64, N, 64, 0);
      gemm_kernel<64, true, true><<<dim3(NB, 1), B, 0, stream>>>(Ain, 192, Wq, 64, zer,  Qb, 64, N, 64, 0);
    }
    hipMemsetAsync(stE, 0, 128 * 4, stream);
    passA_kernel<<<6250, B, 0, stream>>>(P, Qb, src, dst, stE, E);
    fold_kernel<<<1, B, 0, stream>>>(stE, 1.f / (float)E, ga_k, bea_k, Wb_k, bb_k, W2, b2, 64, 64);
    hipMemsetAsync(stE2, 0, 128 * 4, stream);
    hipMemsetAsync(agg, 0, (size_t)N * 64 * 4, stream);
    passBC_kernel<<<cdiv(E, 256), B, 0, stream>>>(P, Qb, src, dst, W2, b2, agg, stE2, E);
    bncoef_kernel<<<1, 64, 0, stream>>>(stE2, 1.f / (float)E, gb_k, beb_k, aC, bC, 64);
    fixup_kernel<<<cdiv(N * 64, 256), B, 0, stream>>>(agg, deg, aC, bC, xcat + (size_t)k * 64, 192, N);
  }

  // node MLP (u_l over dead P/Q/agg; u1/u2 over dead xcat)
  gemm_kernel<64, true, true><<<dim3(NB, 4), B, 0, stream>>>(xcat, 192, pf + hoff[17], 256,
                                                             pf + hoff[18], u_l, 256, N, 192, 1);
  hipMemsetAsync(stN, 0, 512 * 4, stream);
  statsN_kernel<256><<<2048, B, 0, stream>>>(u_l, stN, N);
  fold_kernel<<<1, B, 0, stream>>>(stN, 1.f / (float)N, pf + hoff[19], pf + hoff[20],
                                   pf + hoff[21], pf + hoff[22], Wm1F, bm1F, 256, 64);
  gemm_kernel<64, true, true><<<dim3(NB, 1), B, 0, stream>>>(u_l, 256, Wm1F, 64, bm1F, u1, 64, N, 256, 1);
  hipMemsetAsync(stN, 0, 128 * 4, stream);
  statsN_kernel<64><<<2048, B, 0, stream>>>(u1, stN, N);
  fold_kernel<<<1, B, 0, stream>>>(stN, 1.f / (float)N, pf + hoff[23], pf + hoff[24],
                                   pf + hoff[25], pf + hoff[26], Wm2F, bm2F, 64, 32);
  gemm_kernel<32, true, true><<<dim3(NB, 1), B, 0, stream>>>(u1, 64, Wm2F, 32, bm2F, u2, 32, N, 64, 1);
  hipMemsetAsync(stN, 0, 64 * 4, stream);
  statsN_kernel<32><<<2048, B, 0, stream>>>(u2, stN, N);
  fold_kernel<<<1, B, 0, stream>>>(stN, 1.f / (float)N, pf + hoff[27], pf + hoff[28],
                                   pf + hoff[29], pf + hoff[30], WoF, boF, 32, 24);
  head_kernel<<<cdiv(N, 256), B, 0, stream>>>(u2, WoF, boF, d_out, N, flag);
}

// Round 5
// 2613.558 us; speedup vs baseline: 1.5417x; 1.5417x over previous
//
#include <hip/hip_runtime.h>
#include <hip/hip_bf16.h>

#define EPS 1e-5f
typedef unsigned short bfr;   // raw bf16 bits
typedef unsigned short hfr;   // raw f16 bits

static inline int cdiv(int a, int b){ return (a + b - 1) / b; }

__device__ __forceinline__ float bf2f(bfr u){ return __uint_as_float((unsigned)u << 16); }
__device__ __forceinline__ bfr f2bf(float f){
  unsigned u = __float_as_uint(f);
  u += 0x7fffu + ((u >> 16) & 1u);   // round-to-nearest-even
  return (bfr)(u >> 16);
}
__device__ __forceinline__ unsigned pack2bf(float a, float b){
  return (unsigned)f2bf(a) | ((unsigned)f2bf(b) << 16);
}
// ---- f16 storage converters ----
__device__ __forceinline__ float h2f(hfr u){ _Float16 h; __builtin_memcpy(&h, &u, 2); return (float)h; }
__device__ __forceinline__ hfr f2h(float f){ _Float16 h = (_Float16)f; hfr u; __builtin_memcpy(&u, &h, 2); return u; }
__device__ __forceinline__ unsigned pack2h(float a, float b){
  return (unsigned)f2h(a) | ((unsigned)f2h(b) << 16);
}

// ---------------- dtype detection (bf16 vs f32 inputs) ----------------
__global__ __launch_bounds__(256) void detect_kernel(const bfr* __restrict__ xr, int nwords, int* __restrict__ flag){
  int i = threadIdx.x;
  int bad = 0;
  if (i < nwords){
    bfr lo = xr[2 * i];
    int e = (lo >> 7) & 0xFF;
    bool plausible = ((lo & 0x7FFF) == 0) || (e >= 97 && e <= 157);
    bad = plausible ? 0 : 1;
  }
  __shared__ int s[256];
  s[threadIdx.x] = bad; __syncthreads();
  for (int st = 128; st; st >>= 1){
    if (threadIdx.x < st) s[threadIdx.x] += s[threadIdx.x + st];
    __syncthreads();
  }
  if (threadIdx.x == 0) *flag = (s[0] > 32) ? 1 : 0;   // 1 => inputs are f32
}

// ---------------- batched adaptive convert: all float tensors -> f32 ws ----------------
#define NPAR 31
struct ParamPtrs { const void* p[NPAR]; };
struct ParamOfs  { int off[NPAR + 1]; };

__global__ __launch_bounds__(256) void acvt_batch_kernel(ParamPtrs pp, ParamOfs po,
                                                         float* __restrict__ out, int total,
                                                         const int* __restrict__ flag){
  int g = blockIdx.x * 256 + threadIdx.x;
  if (g >= total) return;
  int isf = *flag;
  int t = 0;
  while (po.off[t + 1] <= g) ++t;
  int i = g - po.off[t];
  out[g] = isf ? ((const float*)pp.p[t])[i] : bf2f(((const bfr*)pp.p[t])[i]);
}

// ---------------- counting sort of edges by dst ----------------
__global__ __launch_bounds__(256) void deg_kernel(const int* __restrict__ dst, int* __restrict__ deg, int E){
  int e = blockIdx.x * 256 + threadIdx.x;
  if (e < E) atomicAdd(&deg[dst[e]], 1);
}

// single-block exclusive scan: deg[N] -> row_off[N+1], copy to cur
__global__ __launch_bounds__(256) void scan_kernel(const int* __restrict__ deg, int* __restrict__ row_off,
                                                   int* __restrict__ cur, int N){
  __shared__ int bs[256];
  const int T = 256;
  int chunk = (N + T - 1) / T;
  int t = threadIdx.x;
  int lo = t * chunk, hi = min(lo + chunk, N);
  int s = 0;
  for (int i = lo; i < hi; ++i) s += deg[i];
  bs[t] = s; __syncthreads();
  for (int st = 1; st < T; st <<= 1){
    int v = (t >= st) ? bs[t - st] : 0;
    __syncthreads();
    bs[t] += v;
    __syncthreads();
  }
  int base = (t == 0) ? 0 : bs[t - 1];
  for (int i = lo; i < hi; ++i){
    row_off[i] = base; cur[i] = base;
    base += deg[i];
  }
  if (t == T - 1) row_off[N] = base;
}

__global__ __launch_bounds__(256) void scatter_kernel(const int* __restrict__ src, const int* __restrict__ dst,
                                                      int* __restrict__ cur, int* __restrict__ ssrc, int E){
  int e = blockIdx.x * 256 + threadIdx.x;
  if (e < E){
    int p = atomicAdd(&cur[dst[e]], 1);
    ssrc[p] = src[e];
  }
}

// Wfull [2d,64] f32 -> Wt = top-bot, Wq = bot
__global__ __launch_bounds__(256) void prep_pq_kernel(const float* __restrict__ W, float* __restrict__ Wt,
                                                      float* __restrict__ Wq, int d){
  int i = blockIdx.x * 256 + threadIdx.x;
  if (i < d * 64){ Wt[i] = W[i] - W[d * 64 + i]; Wq[i] = W[d * 64 + i]; }
}

// ---------------- generic row-per-thread GEMM: out = [relu](A @ W + bias) ----------------
template<int NOUT, bool AHF, bool OHF>
__global__ __launch_bounds__(256) void gemm_kernel(const void* __restrict__ Av, int lda,
                                                   const float* __restrict__ W, int ldw,
                                                   const float* __restrict__ bias,
                                                   void* __restrict__ Ov, int ldo,
                                                   int nrows, int K, int relu){
  __shared__ float Ws[64 * NOUT];
  const int ct = blockIdx.y * NOUT;
  const int row = blockIdx.x * 256 + threadIdx.x;
  float acc[NOUT];
#pragma unroll
  for (int c = 0; c < NOUT; ++c) acc[c] = 0.f;
  const hfr* Ah = (const hfr*)Av;
  const float* Af = (const float*)Av;
  for (int k0 = 0; k0 < K; k0 += 64){
    int kc = min(64, K - k0);
    int tot = kc * NOUT;
    for (int i = threadIdx.x; i < tot; i += 256){
      int kk = i / NOUT, cc = i - kk * NOUT;
      Ws[i] = W[(size_t)(k0 + kk) * ldw + ct + cc];
    }
    __syncthreads();
    if (row < nrows){
      const size_t basei = (size_t)row * lda + k0;
      for (int k = 0; k < kc; ++k){
        float a = AHF ? h2f(Ah[basei + k]) : Af[basei + k];
#pragma unroll
        for (int c = 0; c < NOUT; ++c) acc[c] += a * Ws[k * NOUT + c];
      }
    }
    __syncthreads();
  }
  if (row >= nrows) return;
#pragma unroll
  for (int c = 0; c < NOUT; ++c){
    float v = acc[c] + bias[ct + c];
    acc[c] = relu ? fmaxf(v, 0.f) : v;
  }
  if (OHF){
    unsigned p[NOUT / 2];
#pragma unroll
    for (int c = 0; c < NOUT; c += 2) p[c / 2] = pack2h(acc[c], acc[c + 1]);
    uint4* op = (uint4*)((hfr*)Ov + (size_t)row * ldo + ct);
#pragma unroll
    for (int i = 0; i < NOUT / 8; ++i) op[i] = make_uint4(p[4*i], p[4*i+1], p[4*i+2], p[4*i+3]);
  } else {
    float4* op = (float4*)((float*)Ov + (size_t)row * ldo + ct);
#pragma unroll
    for (int i = 0; i < NOUT / 4; ++i) op[i] = make_float4(acc[4*i], acc[4*i+1], acc[4*i+2], acc[4*i+3]);
  }
}

// ---------------- passA (sorted): BN1 stats of h1 = relu(P[n]+Q[src]), wave-per-node ----------------
__global__ __launch_bounds__(256) void passA_kernel(const hfr* __restrict__ P, const hfr* __restrict__ Q,
                                                    const int* __restrict__ ssrc, const int* __restrict__ row_off,
                                                    float* __restrict__ stats, int N){
  const int lane = threadIdx.x & 63;
  const int wid = (blockIdx.x * 256 + threadIdx.x) >> 6;
  const int nw = (gridDim.x * 256) >> 6;
  float sum = 0.f, sq = 0.f;
  for (int n = wid; n < N; n += nw){
    float pn = h2f(P[(size_t)n * 64 + lane]);
    int e1 = row_off[n + 1];
    for (int e = row_off[n]; e < e1; ++e){
      float v = fmaxf(pn + h2f(Q[(size_t)ssrc[e] * 64 + lane]), 0.f);
      sum += v; sq += v * v;
    }
  }
  atomicAdd(&stats[lane], sum);
  atomicAdd(&stats[64 + lane], sq);
}

// ---------------- fold BN(stats,g,be) into next Lin ----------------
__global__ __launch_bounds__(256) void fold_kernel(const float* __restrict__ stats, float cntInv,
                                                   const float* __restrict__ g, const float* __restrict__ be,
                                                   const float* __restrict__ Wn, const float* __restrict__ bn,
                                                   float* __restrict__ Wo, float* __restrict__ bo, int K, int C){
  __shared__ float a[256], bb[256];
  for (int k = threadIdx.x; k < K; k += 256){
    float mu = stats[k] * cntInv;
    float var = stats[K + k] * cntInv - mu * mu;
    float ai = g[k] * rsqrtf(var + EPS);
    a[k] = ai; bb[k] = be[k] - ai * mu;
  }
  __syncthreads();
  int tot = K * C;
  for (int i = threadIdx.x; i < tot; i += 256) Wo[i] = a[i / C] * Wn[i];
  for (int c = threadIdx.x; c < C; c += 256){
    float s = bn[c];
    for (int k = 0; k < K; ++k) s += bb[k] * Wn[(size_t)k * C + c];
    bo[c] = s;
  }
}

__global__ void bncoef_kernel(const float* __restrict__ stats, float cntInv,
                              const float* __restrict__ g, const float* __restrict__ be,
                              float* __restrict__ a, float* __restrict__ b, int C){
  int c = threadIdx.x;
  if (c < C){
    float mu = stats[c] * cntInv;
    float var = stats[C + c] * cntInv - mu * mu;
    float ai = g[c] * rsqrtf(var + EPS);
    a[c] = ai; b[c] = be[c] - ai * mu;
  }
}

// ---------------- passBC (sorted): wave-per-node. h2 GEMM + BN2 stats + register segment-max ----------------
// lane = channel. W2 column in 64 VGPRs. h staged per-wave in LDS (intra-wave, no barriers).
// Plain coalesced store of max per node — zero atomics on agg.
__global__ __launch_bounds__(256) void passBC_kernel(const hfr* __restrict__ P, const hfr* __restrict__ Q,
                                                     const int* __restrict__ ssrc, const int* __restrict__ row_off,
                                                     const float* __restrict__ W2, const float* __restrict__ b2,
                                                     float* __restrict__ agg, float* __restrict__ stats, int N){
  __shared__ float ht[4][8][64];
  const int lane = threadIdx.x & 63;
  const int wib = threadIdx.x >> 6;
  const int wid = (blockIdx.x * 256 + threadIdx.x) >> 6;
  const int nw = (gridDim.x * 256) >> 6;
  float Wr[64];
#pragma unroll
  for (int k = 0; k < 64; ++k) Wr[k] = W2[k * 64 + lane];
  const float bc = b2[lane];
  float (*hl)[64] = ht[wib];
  float sum = 0.f, sq = 0.f;
  for (int n = wid; n < N; n += nw){
    float pn = h2f(P[(size_t)n * 64 + lane]);
    const int e0 = row_off[n], e1 = row_off[n + 1];
    float mx = 0.f;                       // relu outputs >= 0, so 0 is identity for max
    for (int eb = e0; eb < e1; eb += 8){
      int nb = min(8, e1 - eb);
      for (int j = 0; j < nb; ++j)
        hl[j][lane] = fmaxf(pn + h2f(Q[(size_t)ssrc[eb + j] * 64 + lane]), 0.f);
      // intra-wave LDS dependency: compiler emits lgkmcnt wait, no barrier needed
      for (int j = 0; j < nb; ++j){
        float acc = bc;
#pragma unroll
        for (int k4 = 0; k4 < 16; ++k4){
          float4 h4 = *(const float4*)&hl[j][k4 * 4];   // broadcast ds_read_b128
          acc += h4.x * Wr[4*k4] + h4.y * Wr[4*k4+1] + h4.z * Wr[4*k4+2] + h4.w * Wr[4*k4+3];
        }
        float v = fmaxf(acc, 0.f);
        mx = fmaxf(mx, v);
        sum += v; sq += v * v;
      }
    }
    agg[(size_t)n * 64 + lane] = mx;      // plain coalesced store (deg==0 -> 0, fixup masks)
  }
  atomicAdd(&stats[lane], sum);
  atomicAdd(&stats[64 + lane], sq);
}

// x_next = deg>0 ? a*max + b : 0, f16 into xcat column slice
__global__ __launch_bounds__(256) void fixup_kernel(const float* __restrict__ agg, const int* __restrict__ deg,
                                                    const float* __restrict__ a, const float* __restrict__ b,
                                                    hfr* __restrict__ xout, int ldx, int N){
  int t = blockIdx.x * 256 + threadIdx.x;
  if (t >= N * 64) return;
  int n = t >> 6, c = t & 63;
  float v = 0.f;
  if (deg[n] > 0) v = a[c] * agg[t] + b[c];
  xout[(size_t)n * ldx + c] = f2h(v);
}

// ---------------- node BN stats over f16 activations ----------------
template<int C>
__global__ __launch_bounds__(256) void statsN_kernel(const hfr* __restrict__ u, float* __restrict__ stats, int N){
  constexpr int RP = 256 / C;
  const int c = threadIdx.x % C, j = threadIdx.x / C;
  float sum = 0.f, sq = 0.f;
  for (int r = blockIdx.x * RP + j; r < N; r += gridDim.x * RP){
    float v = h2f(u[(size_t)r * C + c]);
    sum += v; sq += v * v;
  }
  __shared__ float ls[256], lq[256];
  ls[threadIdx.x] = sum; lq[threadIdx.x] = sq;
  __syncthreads();
  if (threadIdx.x < C){
    float s = 0.f, q = 0.f;
#pragma unroll
    for (int jj = 0; jj < RP; ++jj){ s += ls[jj * C + c]; q += lq[jj * C + c]; }
    atomicAdd(&stats[c], s); atomicAdd(&stats[C + c], q);
  }
}

// ---------------- head: logits + log_softmax, dtype-adaptive store ----------------
__global__ __launch_bounds__(256) void head_kernel(const hfr* __restrict__ u2,
                                                   const float* __restrict__ Wo, const float* __restrict__ bo,
                                                   void* __restrict__ out, int N, const int* __restrict__ flag){
  __shared__ float Ws[32 * 24];
  __shared__ float bs[24];
  for (int i = threadIdx.x; i < 32 * 24; i += 256) Ws[i] = Wo[i];
  if (threadIdx.x < 24) bs[threadIdx.x] = bo[threadIdx.x];
  __syncthreads();
  int r = blockIdx.x * 256 + threadIdx.x;
  if (r >= N) return;
  int isf = *flag;
  float l[24];
#pragma unroll
  for (int c = 0; c < 24; ++c) l[c] = bs[c];
  const hfr* up = u2 + (size_t)r * 32;
#pragma unroll
  for (int k = 0; k < 32; ++k){
    float v = h2f(up[k]);
#pragma unroll
    for (int c = 0; c < 24; ++c) l[c] += v * Ws[k * 24 + c];
  }
  float m = l[0];
#pragma unroll
  for (int c = 1; c < 24; ++c) m = fmaxf(m, l[c]);
  float s = 0.f;
#pragma unroll
  for (int c = 0; c < 24; ++c) s += expf(l[c] - m);
  float lse = m + logf(s);
  if (isf){
    float4* op = (float4*)((float*)out + (size_t)r * 24);
#pragma unroll
    for (int i = 0; i < 6; ++i)
      op[i] = make_float4(l[4*i] - lse, l[4*i+1] - lse, l[4*i+2] - lse, l[4*i+3] - lse);
  } else {
    unsigned p[12];
#pragma unroll
    for (int c = 0; c < 24; c += 2) p[c / 2] = pack2bf(l[c] - lse, l[c + 1] - lse);
    uint4* op = (uint4*)((bfr*)out + (size_t)r * 24);
#pragma unroll
    for (int i = 0; i < 3; ++i) op[i] = make_uint4(p[4*i], p[4*i+1], p[4*i+2], p[4*i+3]);
  }
}

// ---------------- host ----------------
// Footprint ~51 MB. Aliases disjoint in time: u_l over P+Q+agg (dead after conv
// loop); u1/u2 over xcat (dead after lin1). Edges counting-sorted by dst once.
extern "C" void kernel_launch(void* const* d_in, const int* in_sizes, int n_in,
                              void* d_out, int out_size, void* d_ws, size_t ws_size,
                              hipStream_t stream){
  const int N = in_sizes[0] / 6;
  const int E = in_sizes[31] / 2;
  const int* edge = (const int*)d_in[31];
  const int* src = edge;
  const int* dst = edge + E;

  size_t off = 0; char* basep = (char*)d_ws;
  auto alloc = [&](size_t bytes) -> void* {
    void* p = basep + off;
    off = (off + bytes + 255) & ~(size_t)255;
    return p;
  };
  float* Wt   = (float*)alloc(64 * 64 * 4);
  float* Wq   = (float*)alloc(64 * 64 * 4);
  float* W2   = (float*)alloc(64 * 64 * 4);
  float* b2   = (float*)alloc(64 * 4);
  float* Wm1F = (float*)alloc(256 * 64 * 4);
  float* bm1F = (float*)alloc(64 * 4);
  float* Wm2F = (float*)alloc(64 * 32 * 4);
  float* bm2F = (float*)alloc(32 * 4);
  float* WoF  = (float*)alloc(32 * 24 * 4);
  float* boF  = (float*)alloc(24 * 4);
  float* zer  = (float*)alloc(64 * 4);
  float* stE  = (float*)alloc(128 * 4);
  float* stE2 = (float*)alloc(128 * 4);
  float* stN  = (float*)alloc(512 * 4);
  float* aC   = (float*)alloc(64 * 4);
  float* bC   = (float*)alloc(64 * 4);
  int*   flag = (int*)  alloc(4);
  int*   deg  = (int*)  alloc((size_t)N * 4);
  int*   rowo = (int*)  alloc((size_t)(N + 1) * 4);
  int*   cur  = (int*)  alloc((size_t)N * 4);
  int*   ssrc = (int*)  alloc((size_t)E * 4);

  // f32 staging of all float inputs (params 1..30 then x as slot 30)
  ParamPtrs pp; ParamOfs po;
  int hoff[32]; int total = 0;
  for (int s = 0; s < NPAR; ++s){
    int idx = (s < 30) ? (s + 1) : 0;
    pp.p[s] = d_in[idx];
    po.off[s] = total;
    hoff[idx] = total;
    total += in_sizes[idx];
  }
  po.off[NPAR] = total;
  float* pf = (float*)alloc((size_t)total * 4);

  // big buffers: P,Q,agg contiguous (u_l alias needs 25.6MB), then xcat
  hfr*   P    = (hfr*)  alloc((size_t)N * 64 * 2);    // 6.4 MB
  hfr*   Qb   = (hfr*)  alloc((size_t)N * 64 * 2);    // 6.4 MB
  float* agg  = (float*)alloc((size_t)N * 64 * 4);    // 12.8 MB
  hfr*   xcat = (hfr*)  alloc((size_t)N * 192 * 2);   // 19.2 MB
  hfr* u_l = (hfr*)P;                 // [N,256] f16 over P+Q+agg
  hfr* u1  = xcat;                    // [N,64]  f16
  hfr* u2  = xcat + (size_t)N * 64;   // [N,32]  f16
  (void)ws_size; (void)n_in; (void)out_size;

  dim3 B(256);
  detect_kernel<<<1, B, 0, stream>>>((const bfr*)d_in[0], 256, flag);
  acvt_batch_kernel<<<cdiv(total, 256), B, 0, stream>>>(pp, po, pf, total, flag);

  // counting sort by dst
  hipMemsetAsync(deg, 0, (size_t)N * 4, stream);
  hipMemsetAsync(zer, 0, 64 * 4, stream);
  deg_kernel<<<cdiv(E, 256), B, 0, stream>>>(dst, deg, E);
  scan_kernel<<<1, B, 0, stream>>>(deg, rowo, cur, N);
  scatter_kernel<<<cdiv(E, 256), B, 0, stream>>>(src, dst, cur, ssrc, E);

  const int NB = cdiv(N, 256);
  const int GW = 2048;   // grid-stride wave blocks for edge passes
  for (int k = 0; k < 3; ++k){
    const float *Wa_k, *ba_k, *ga_k, *bea_k, *Wb_k, *bb_k, *gb_k, *beb_k;
    int d;
    if (k == 0){
      Wa_k = pf + hoff[1]; ba_k = pf + hoff[2]; ga_k = pf + hoff[3]; bea_k = pf + hoff[4];
      Wb_k = pf + hoff[5]; bb_k = pf + hoff[6]; gb_k = pf + hoff[7]; beb_k = pf + hoff[8];
      d = 6;
    } else {
      int kk = k - 1;
      Wa_k = pf + hoff[9]  + (size_t)kk * 128 * 64;
      ba_k = pf + hoff[10] + kk * 64;
      ga_k = pf + hoff[11] + kk * 64;
      bea_k= pf + hoff[12] + kk * 64;
      Wb_k = pf + hoff[13] + (size_t)kk * 64 * 64;
      bb_k = pf + hoff[14] + kk * 64;
      gb_k = pf + hoff[15] + kk * 64;
      beb_k= pf + hoff[16] + kk * 64;
      d = 64;
    }
    prep_pq_kernel<<<cdiv(d * 64, 256), B, 0, stream>>>(Wa_k, Wt, Wq, d);
    if (k == 0){
      gemm_kernel<64, false, true><<<dim3(NB, 1), B, 0, stream>>>(pf + hoff[0], 6, Wt, 64, ba_k, P,  64, N, 6, 0);
      gemm_kernel<64, false, true><<<dim3(NB, 1), B, 0, stream>>>(pf + hoff[0], 6, Wq, 64, zer,  Qb, 64, N, 6, 0);
    } else {
      const hfr* Ain = xcat + (size_t)(k - 1) * 64;
      gemm_kernel<64, true, true><<<dim3(NB, 1), B, 0, stream>>>(Ain, 192, Wt, 64, ba_k, P,  64, N, 64, 0);
      gemm_kernel<64, true, true><<<dim3(NB, 1), B, 0, stream>>>(Ain, 192, Wq, 64, zer,  Qb, 64, N, 64, 0);
    }
    hipMemsetAsync(stE, 0, 128 * 4, stream);
    passA_kernel<<<GW, B, 0, stream>>>(P, Qb, ssrc, rowo, stE, N);
    fold_kernel<<<1, B, 0, stream>>>(stE, 1.f / (float)E, ga_k, bea_k, Wb_k, bb_k, W2, b2, 64, 64);
    hipMemsetAsync(stE2, 0, 128 * 4, stream);
    passBC_kernel<<<GW, B, 0, stream>>>(P, Qb, ssrc, rowo, W2, b2, agg, stE2, N);
    bncoef_kernel<<<1, 64, 0, stream>>>(stE2, 1.f / (float)E, gb_k, beb_k, aC, bC, 64);
    fixup_kernel<<<cdiv(N * 64, 256), B, 0, stream>>>(agg, deg, aC, bC, xcat + (size_t)k * 64, 192, N);
  }

  // node MLP (u_l over dead P/Q/agg; u1/u2 over dead xcat)
  gemm_kernel<64, true, true><<<dim3(NB, 4), B, 0, stream>>>(xcat, 192, pf + hoff[17], 256,
                                                             pf + hoff[18], u_l, 256, N, 192, 1);
  hipMemsetAsync(stN, 0, 512 * 4, stream);
  statsN_kernel<256><<<2048, B, 0, stream>>>(u_l, stN, N);
  fold_kernel<<<1, B, 0, stream>>>(stN, 1.f / (float)N, pf + hoff[19], pf + hoff[20],
                                   pf + hoff[21], pf + hoff[22], Wm1F, bm1F, 256, 64);
  gemm_kernel<64, true, true><<<dim3(NB, 1), B, 0, stream>>>(u_l, 256, Wm1F, 64, bm1F, u1, 64, N, 256, 1);
  hipMemsetAsync(stN, 0, 128 * 4, stream);
  statsN_kernel<64><<<2048, B, 0, stream>>>(u1, stN, N);
  fold_kernel<<<1, B, 0, stream>>>(stN, 1.f / (float)N, pf + hoff[23], pf + hoff[24],
                                   pf + hoff[25], pf + hoff[26], Wm2F, bm2F, 64, 32);
  gemm_kernel<32, true, true><<<dim3(NB, 1), B, 0, stream>>>(u1, 64, Wm2F, 32, bm2F, u2, 32, N, 64, 1);
  hipMemsetAsync(stN, 0, 64 * 4, stream);
  statsN_kernel<32><<<2048, B, 0, stream>>>(u2, stN, N);
  fold_kernel<<<1, B, 0, stream>>>(stN, 1.f / (float)N, pf + hoff[27], pf + hoff[28],
                                   pf + hoff[29], pf + hoff[30], WoF, boF, 32, 24);
  head_kernel<<<cdiv(N, 256), B, 0, stream>>>(u2, WoF, boF, d_out, N, flag);
}

// Round 6
// 2561.606 us; speedup vs baseline: 1.5730x; 1.0203x over previous
//
#include <hip/hip_runtime.h>
#include <hip/hip_bf16.h>

#define EPS 1e-5f
typedef unsigned short bfr;   // raw bf16 bits
typedef unsigned short hfr;   // raw f16 bits
typedef _Float16 h2v __attribute__((ext_vector_type(2)));

#if defined(__has_builtin)
#if __has_builtin(__builtin_amdgcn_fdot2)
#define HAS_FDOT2 1
#endif
#endif

static inline int cdiv(int a, int b){ return (a + b - 1) / b; }

__device__ __forceinline__ float bf2f(bfr u){ return __uint_as_float((unsigned)u << 16); }
__device__ __forceinline__ bfr f2bf(float f){
  unsigned u = __float_as_uint(f);
  u += 0x7fffu + ((u >> 16) & 1u);
  return (bfr)(u >> 16);
}
__device__ __forceinline__ unsigned pack2bf(float a, float b){
  return (unsigned)f2bf(a) | ((unsigned)f2bf(b) << 16);
}
__device__ __forceinline__ float h2f(hfr u){ _Float16 h; __builtin_memcpy(&h, &u, 2); return (float)h; }
__device__ __forceinline__ _Float16 asH(hfr u){ _Float16 h; __builtin_memcpy(&h, &u, 2); return h; }
__device__ __forceinline__ hfr bitsH(_Float16 h){ hfr u; __builtin_memcpy(&u, &h, 2); return u; }
__device__ __forceinline__ hfr f2h(float f){ return bitsH((_Float16)f); }
__device__ __forceinline__ unsigned pack2h(float a, float b){
  return (unsigned)f2h(a) | ((unsigned)f2h(b) << 16);
}
__device__ __forceinline__ h2v u2h2(unsigned u){ h2v r; __builtin_memcpy(&r, &u, 4); return r; }
__device__ __forceinline__ float dot2(h2v a, h2v b, float c){
#ifdef HAS_FDOT2
  return __builtin_amdgcn_fdot2(a, b, c, false);
#else
  return c + (float)a.x * (float)b.x + (float)a.y * (float)b.y;
#endif
}

// ---------------- dtype detection (bf16 vs f32 inputs) ----------------
__global__ __launch_bounds__(256) void detect_kernel(const bfr* __restrict__ xr, int nwords, int* __restrict__ flag){
  int i = threadIdx.x;
  int bad = 0;
  if (i < nwords){
    bfr lo = xr[2 * i];
    int e = (lo >> 7) & 0xFF;
    bool plausible = ((lo & 0x7FFF) == 0) || (e >= 97 && e <= 157);
    bad = plausible ? 0 : 1;
  }
  __shared__ int s[256];
  s[threadIdx.x] = bad; __syncthreads();
  for (int st = 128; st; st >>= 1){
    if (threadIdx.x < st) s[threadIdx.x] += s[threadIdx.x + st];
    __syncthreads();
  }
  if (threadIdx.x == 0) *flag = (s[0] > 32) ? 1 : 0;
}

// ---------------- batched adaptive convert ----------------
#define NPAR 31
struct ParamPtrs { const void* p[NPAR]; };
struct ParamOfs  { int off[NPAR + 1]; };

__global__ __launch_bounds__(256) void acvt_batch_kernel(ParamPtrs pp, ParamOfs po,
                                                         float* __restrict__ out, int total,
                                                         const int* __restrict__ flag){
  int g = blockIdx.x * 256 + threadIdx.x;
  if (g >= total) return;
  int isf = *flag;
  int t = 0;
  while (po.off[t + 1] <= g) ++t;
  int i = g - po.off[t];
  out[g] = isf ? ((const float*)pp.p[t])[i] : bf2f(((const bfr*)pp.p[t])[i]);
}

// ---------------- counting sort of edges by dst ----------------
__global__ __launch_bounds__(256) void deg_kernel(const int* __restrict__ dst, int* __restrict__ deg, int E){
  int e = blockIdx.x * 256 + threadIdx.x;
  if (e < E) atomicAdd(&deg[dst[e]], 1);
}

__global__ __launch_bounds__(256) void scan_kernel(const int* __restrict__ deg, int* __restrict__ row_off,
                                                   int* __restrict__ cur, int N){
  __shared__ int bs[256];
  const int T = 256;
  int chunk = (N + T - 1) / T;
  int t = threadIdx.x;
  int lo = t * chunk, hi = min(lo + chunk, N);
  int s = 0;
  for (int i = lo; i < hi; ++i) s += deg[i];
  bs[t] = s; __syncthreads();
  for (int st = 1; st < T; st <<= 1){
    int v = (t >= st) ? bs[t - st] : 0;
    __syncthreads();
    bs[t] += v;
    __syncthreads();
  }
  int base = (t == 0) ? 0 : bs[t - 1];
  for (int i = lo; i < hi; ++i){
    row_off[i] = base; cur[i] = base;
    base += deg[i];
  }
  if (t == T - 1) row_off[N] = base;
}

__global__ __launch_bounds__(256) void scatter_kernel(const int* __restrict__ src, const int* __restrict__ dst,
                                                      int* __restrict__ cur, int* __restrict__ ssrc, int E){
  int e = blockIdx.x * 256 + threadIdx.x;
  if (e < E){
    int p = atomicAdd(&cur[dst[e]], 1);
    ssrc[p] = src[e];
  }
}

__global__ __launch_bounds__(256) void prep_pq_kernel(const float* __restrict__ W, float* __restrict__ Wt,
                                                      float* __restrict__ Wq, int d){
  int i = blockIdx.x * 256 + threadIdx.x;
  if (i < d * 64){ Wt[i] = W[i] - W[d * 64 + i]; Wq[i] = W[d * 64 + i]; }
}

// ---------------- generic row-per-thread GEMM ----------------
template<int NOUT, bool AHF, bool OHF>
__global__ __launch_bounds__(256) void gemm_kernel(const void* __restrict__ Av, int lda,
                                                   const float* __restrict__ W, int ldw,
                                                   const float* __restrict__ bias,
                                                   void* __restrict__ Ov, int ldo,
                                                   int nrows, int K, int relu){
  __shared__ float Ws[64 * NOUT];
  const int ct = blockIdx.y * NOUT;
  const int row = blockIdx.x * 256 + threadIdx.x;
  float acc[NOUT];
#pragma unroll
  for (int c = 0; c < NOUT; ++c) acc[c] = 0.f;
  const hfr* Ah = (const hfr*)Av;
  const float* Af = (const float*)Av;
  for (int k0 = 0; k0 < K; k0 += 64){
    int kc = min(64, K - k0);
    int tot = kc * NOUT;
    for (int i = threadIdx.x; i < tot; i += 256){
      int kk = i / NOUT, cc = i - kk * NOUT;
      Ws[i] = W[(size_t)(k0 + kk) * ldw + ct + cc];
    }
    __syncthreads();
    if (row < nrows){
      const size_t basei = (size_t)row * lda + k0;
      for (int k = 0; k < kc; ++k){
        float a = AHF ? h2f(Ah[basei + k]) : Af[basei + k];
#pragma unroll
        for (int c = 0; c < NOUT; ++c) acc[c] += a * Ws[k * NOUT + c];
      }
    }
    __syncthreads();
  }
  if (row >= nrows) return;
#pragma unroll
  for (int c = 0; c < NOUT; ++c){
    float v = acc[c] + bias[ct + c];
    acc[c] = relu ? fmaxf(v, 0.f) : v;
  }
  if (OHF){
    unsigned p[NOUT / 2];
#pragma unroll
    for (int c = 0; c < NOUT; c += 2) p[c / 2] = pack2h(acc[c], acc[c + 1]);
    uint4* op = (uint4*)((hfr*)Ov + (size_t)row * ldo + ct);
#pragma unroll
    for (int i = 0; i < NOUT / 8; ++i) op[i] = make_uint4(p[4*i], p[4*i+1], p[4*i+2], p[4*i+3]);
  } else {
    float4* op = (float4*)((float*)Ov + (size_t)row * ldo + ct);
#pragma unroll
    for (int i = 0; i < NOUT / 4; ++i) op[i] = make_float4(acc[4*i], acc[4*i+1], acc[4*i+2], acc[4*i+3]);
  }
}

// ---------------- passA (sorted): BN1 stats of h1 = relu_f16(P[n]+Q[src]) ----------------
// f16 add matches passBC's staged h1 exactly (f16 add == f32 add + round for two f16 inputs).
__global__ __launch_bounds__(256) void passA_kernel(const hfr* __restrict__ P, const hfr* __restrict__ Q,
                                                    const int* __restrict__ ssrc, const int* __restrict__ row_off,
                                                    float* __restrict__ stats, int N){
  const int lane = threadIdx.x & 63;
  const int wid = (blockIdx.x * 256 + threadIdx.x) >> 6;
  const int nw = (gridDim.x * 256) >> 6;
  const _Float16 z16 = (_Float16)0;
  float sum = 0.f, sq = 0.f;
  for (int n = wid; n < N; n += nw){
    _Float16 pn = asH(P[(size_t)n * 64 + lane]);
    int e0 = row_off[n], e1 = row_off[n + 1];
    int e = e0;
    for (; e + 1 < e1; e += 2){
      int s0 = ssrc[e], s1 = ssrc[e + 1];
      _Float16 a = pn + asH(Q[(size_t)s0 * 64 + lane]);
      _Float16 b = pn + asH(Q[(size_t)s1 * 64 + lane]);
      float va = (a < z16) ? 0.f : (float)a;
      float vb = (b < z16) ? 0.f : (float)b;
      sum += va + vb; sq += va * va + vb * vb;
    }
    if (e < e1){
      _Float16 a = pn + asH(Q[(size_t)ssrc[e] * 64 + lane]);
      float va = (a < z16) ? 0.f : (float)a;
      sum += va; sq += va * va;
    }
  }
  atomicAdd(&stats[lane], sum);
  atomicAdd(&stats[64 + lane], sq);
}

// ---------------- fold BN(stats,g,be) into next Lin ----------------
__global__ __launch_bounds__(256) void fold_kernel(const float* __restrict__ stats, float cntInv,
                                                   const float* __restrict__ g, const float* __restrict__ be,
                                                   const float* __restrict__ Wn, const float* __restrict__ bn,
                                                   float* __restrict__ Wo, float* __restrict__ bo, int K, int C){
  __shared__ float a[256], bb[256], bsum[256];
  for (int k = threadIdx.x; k < K; k += 256){
    float mu = stats[k] * cntInv;
    float var = stats[K + k] * cntInv - mu * mu;
    float ai = g[k] * rsqrtf(var + EPS);
    a[k] = ai; bb[k] = be[k] - ai * mu;
  }
  __syncthreads();
  int tot = K * C;
  for (int i = threadIdx.x; i < tot; i += 256) Wo[i] = a[i / C] * Wn[i];
  // bias: parts threads per column
  int parts = 256 / C; if (parts < 1) parts = 1;
  int c = threadIdx.x % C, p = threadIdx.x / C;
  float s = 0.f;
  if (p < parts){
    for (int k = p; k < K; k += parts) s += bb[k] * Wn[(size_t)k * C + c];
    bsum[p * C + c] = s;
  }
  __syncthreads();
  if (threadIdx.x < C){
    float t = bn[threadIdx.x];
    for (int pp = 0; pp < parts; ++pp) t += bsum[pp * C + threadIdx.x];
    bo[threadIdx.x] = t;
  }
}

// ---------------- passBC (sorted): wave-per-node, packed-f16 dot2 GEMM + stats + register max ----------------
__global__ __launch_bounds__(256) void passBC_kernel(const hfr* __restrict__ P, const hfr* __restrict__ Q,
                                                     const int* __restrict__ ssrc, const int* __restrict__ row_off,
                                                     const float* __restrict__ W2, const float* __restrict__ b2,
                                                     float* __restrict__ agg, float* __restrict__ stats, int N){
  __shared__ hfr ht[4][8][64];     // 4 KB: per-wave staging of 8 h1 rows (f16)
  const int lane = threadIdx.x & 63;
  const int wib = threadIdx.x >> 6;
  const int wid = (blockIdx.x * 256 + threadIdx.x) >> 6;
  const int nw = (gridDim.x * 256) >> 6;
  const _Float16 z16 = (_Float16)0;
  // W2 column `lane` as 32 packed f16 pairs: Wh[k2] = (W[2k2][lane], W[2k2+1][lane])
  h2v Wh[32];
#pragma unroll
  for (int k2 = 0; k2 < 32; ++k2){
    h2v w; w.x = (_Float16)W2[(2 * k2) * 64 + lane]; w.y = (_Float16)W2[(2 * k2 + 1) * 64 + lane];
    Wh[k2] = w;
  }
  const float bc = b2[lane];
  hfr (*hl)[64] = ht[wib];
  float sum = 0.f, sq = 0.f;
  for (int n = wid; n < N; n += nw){
    _Float16 pn = asH(P[(size_t)n * 64 + lane]);
    const int e0 = row_off[n], e1 = row_off[n + 1];
    float mx = 0.f;
    for (int eb = e0; eb < e1; eb += 8){
      int nb = min(8, e1 - eb);
      for (int j = 0; j < nb; ++j){
        _Float16 s = pn + asH(Q[(size_t)ssrc[eb + j] * 64 + lane]);
        hl[j][lane] = bitsH((s < z16) ? z16 : s);
      }
      // intra-wave LDS dependency: compiler inserts lgkmcnt waits, no barrier needed
      for (int j = 0; j < nb; ++j){
        const uint4* hp = (const uint4*)hl[j];
        float acc = bc;
#pragma unroll
        for (int r = 0; r < 8; ++r){
          uint4 hv = hp[r];                       // 8 f16 = 4 pairs, k = 8r..8r+7
          acc = dot2(u2h2(hv.x), Wh[4*r+0], acc);
          acc = dot2(u2h2(hv.y), Wh[4*r+1], acc);
          acc = dot2(u2h2(hv.z), Wh[4*r+2], acc);
          acc = dot2(u2h2(hv.w), Wh[4*r+3], acc);
        }
        float v = fmaxf(acc, 0.f);
        mx = fmaxf(mx, v);
        sum += v; sq += v * v;
      }
    }
    agg[(size_t)n * 64 + lane] = mx;
  }
  atomicAdd(&stats[lane], sum);
  atomicAdd(&stats[64 + lane], sq);
}

// ---------------- fixup with inlined BN2 coefficients ----------------
__global__ __launch_bounds__(256) void fixup_kernel(const float* __restrict__ agg, const int* __restrict__ deg,
                                                    const float* __restrict__ stats, float cntInv,
                                                    const float* __restrict__ g, const float* __restrict__ be,
                                                    hfr* __restrict__ xout, int ldx, int N){
  int t = blockIdx.x * 256 + threadIdx.x;
  if (t >= N * 64) return;
  int n = t >> 6, c = t & 63;
  float mu = stats[c] * cntInv;
  float var = stats[64 + c] * cntInv - mu * mu;
  float a = g[c] * rsqrtf(var + EPS);
  float b = be[c] - a * mu;
  float v = 0.f;
  if (deg[n] > 0) v = a * agg[t] + b;
  xout[(size_t)n * ldx + c] = f2h(v);
}

// ---------------- node BN stats over f16 activations ----------------
template<int C>
__global__ __launch_bounds__(256) void statsN_kernel(const hfr* __restrict__ u, float* __restrict__ stats, int N){
  constexpr int RP = 256 / C;
  const int c = threadIdx.x % C, j = threadIdx.x / C;
  float sum = 0.f, sq = 0.f;
  for (int r = blockIdx.x * RP + j; r < N; r += gridDim.x * RP){
    float v = h2f(u[(size_t)r * C + c]);
    sum += v; sq += v * v;
  }
  __shared__ float ls[256], lq[256];
  ls[threadIdx.x] = sum; lq[threadIdx.x] = sq;
  __syncthreads();
  if (threadIdx.x < C){
    float s = 0.f, q = 0.f;
#pragma unroll
    for (int jj = 0; jj < RP; ++jj){ s += ls[jj * C + c]; q += lq[jj * C + c]; }
    atomicAdd(&stats[c], s); atomicAdd(&stats[C + c], q);
  }
}

// ---------------- head: logits + log_softmax ----------------
__global__ __launch_bounds__(256) void head_kernel(const hfr* __restrict__ u2,
                                                   const float* __restrict__ Wo, const float* __restrict__ bo,
                                                   void* __restrict__ out, int N, const int* __restrict__ flag){
  __shared__ float Ws[32 * 24];
  __shared__ float bs[24];
  for (int i = threadIdx.x; i < 32 * 24; i += 256) Ws[i] = Wo[i];
  if (threadIdx.x < 24) bs[threadIdx.x] = bo[threadIdx.x];
  __syncthreads();
  int r = blockIdx.x * 256 + threadIdx.x;
  if (r >= N) return;
  int isf = *flag;
  float l[24];
#pragma unroll
  for (int c = 0; c < 24; ++c) l[c] = bs[c];
  const hfr* up = u2 + (size_t)r * 32;
#pragma unroll
  for (int k = 0; k < 32; ++k){
    float v = h2f(up[k]);
#pragma unroll
    for (int c = 0; c < 24; ++c) l[c] += v * Ws[k * 24 + c];
  }
  float m = l[0];
#pragma unroll
  for (int c = 1; c < 24; ++c) m = fmaxf(m, l[c]);
  float s = 0.f;
#pragma unroll
  for (int c = 0; c < 24; ++c) s += expf(l[c] - m);
  float lse = m + logf(s);
  if (isf){
    float4* op = (float4*)((float*)out + (size_t)r * 24);
#pragma unroll
    for (int i = 0; i < 6; ++i)
      op[i] = make_float4(l[4*i] - lse, l[4*i+1] - lse, l[4*i+2] - lse, l[4*i+3] - lse);
  } else {
    unsigned p[12];
#pragma unroll
    for (int c = 0; c < 24; c += 2) p[c / 2] = pack2bf(l[c] - lse, l[c + 1] - lse);
    uint4* op = (uint4*)((bfr*)out + (size_t)r * 24);
#pragma unroll
    for (int i = 0; i < 3; ++i) op[i] = make_uint4(p[4*i], p[4*i+1], p[4*i+2], p[4*i+3]);
  }
}

// ---------------- host ----------------
// Footprint ~51 MB (ws-safe, proven round 3+). Aliases disjoint in time.
extern "C" void kernel_launch(void* const* d_in, const int* in_sizes, int n_in,
                              void* d_out, int out_size, void* d_ws, size_t ws_size,
                              hipStream_t stream){
  const int N = in_sizes[0] / 6;
  const int E = in_sizes[31] / 2;
  const int* edge = (const int*)d_in[31];
  const int* src = edge;
  const int* dst = edge + E;

  size_t off = 0; char* basep = (char*)d_ws;
  auto alloc = [&](size_t bytes) -> void* {
    void* p = basep + off;
    off = (off + bytes + 255) & ~(size_t)255;
    return p;
  };
  float* Wt   = (float*)alloc(64 * 64 * 4);
  float* Wq   = (float*)alloc(64 * 64 * 4);
  float* W2   = (float*)alloc(64 * 64 * 4);
  float* b2   = (float*)alloc(64 * 4);
  float* Wm1F = (float*)alloc(256 * 64 * 4);
  float* bm1F = (float*)alloc(64 * 4);
  float* Wm2F = (float*)alloc(64 * 32 * 4);
  float* bm2F = (float*)alloc(32 * 4);
  float* WoF  = (float*)alloc(32 * 24 * 4);
  float* boF  = (float*)alloc(24 * 4);
  float* zer  = (float*)alloc(64 * 4);
  float* stE  = (float*)alloc(256 * 4);     // [0:128) BN1 stats, [128:256) BN2 stats
  float* stE2 = stE + 128;
  float* stN  = (float*)alloc(512 * 4);
  int*   flag = (int*)  alloc(4);
  int*   deg  = (int*)  alloc((size_t)N * 4);
  int*   rowo = (int*)  alloc((size_t)(N + 1) * 4);
  int*   cur  = (int*)  alloc((size_t)N * 4);
  int*   ssrc = (int*)  alloc((size_t)E * 4);

  ParamPtrs pp; ParamOfs po;
  int hoff[32]; int total = 0;
  for (int s = 0; s < NPAR; ++s){
    int idx = (s < 30) ? (s + 1) : 0;
    pp.p[s] = d_in[idx];
    po.off[s] = total;
    hoff[idx] = total;
    total += in_sizes[idx];
  }
  po.off[NPAR] = total;
  float* pf = (float*)alloc((size_t)total * 4);

  hfr*   P    = (hfr*)  alloc((size_t)N * 64 * 2);
  hfr*   Qb   = (hfr*)  alloc((size_t)N * 64 * 2);
  float* agg  = (float*)alloc((size_t)N * 64 * 4);
  hfr*   xcat = (hfr*)  alloc((size_t)N * 192 * 2);
  hfr* u_l = (hfr*)P;                 // [N,256] f16 over P+Q+agg
  hfr* u1  = xcat;                    // [N,64]  f16
  hfr* u2  = xcat + (size_t)N * 64;   // [N,32]  f16
  (void)ws_size; (void)n_in; (void)out_size;

  dim3 B(256);
  detect_kernel<<<1, B, 0, stream>>>((const bfr*)d_in[0], 256, flag);
  acvt_batch_kernel<<<cdiv(total, 256), B, 0, stream>>>(pp, po, pf, total, flag);

  hipMemsetAsync(deg, 0, (size_t)N * 4, stream);
  hipMemsetAsync(zer, 0, 64 * 4, stream);
  deg_kernel<<<cdiv(E, 256), B, 0, stream>>>(dst, deg, E);
  scan_kernel<<<1, B, 0, stream>>>(deg, rowo, cur, N);
  scatter_kernel<<<cdiv(E, 256), B, 0, stream>>>(src, dst, cur, ssrc, E);

  const int NB = cdiv(N, 256);
  const int GW = 2048;
  const float Einv = 1.f / (float)E;
  for (int k = 0; k < 3; ++k){
    const float *Wa_k, *ba_k, *ga_k, *bea_k, *Wb_k, *bb_k, *gb_k, *beb_k;
    int d;
    if (k == 0){
      Wa_k = pf + hoff[1]; ba_k = pf + hoff[2]; ga_k = pf + hoff[3]; bea_k = pf + hoff[4];
      Wb_k = pf + hoff[5]; bb_k = pf + hoff[6]; gb_k = pf + hoff[7]; beb_k = pf + hoff[8];
      d = 6;
    } else {
      int kk = k - 1;
      Wa_k = pf + hoff[9]  + (size_t)kk * 128 * 64;
      ba_k = pf + hoff[10] + kk * 64;
      ga_k = pf + hoff[11] + kk * 64;
      bea_k= pf + hoff[12] + kk * 64;
      Wb_k = pf + hoff[13] + (size_t)kk * 64 * 64;
      bb_k = pf + hoff[14] + kk * 64;
      gb_k = pf + hoff[15] + kk * 64;
      beb_k= pf + hoff[16] + kk * 64;
      d = 64;
    }
    prep_pq_kernel<<<cdiv(d * 64, 256), B, 0, stream>>>(Wa_k, Wt, Wq, d);
    if (k == 0){
      gemm_kernel<64, false, true><<<dim3(NB, 1), B, 0, stream>>>(pf + hoff[0], 6, Wt, 64, ba_k, P,  64, N, 6, 0);
      gemm_kernel<64, false, true><<<dim3(NB, 1), B, 0, stream>>>(pf + hoff[0], 6, Wq, 64, zer,  Qb, 64, N, 6, 0);
    } else {
      const hfr* Ain = xcat + (size_t)(k - 1) * 64;
      gemm_kernel<64, true, true><<<dim3(NB, 1), B, 0, stream>>>(Ain, 192, Wt, 64, ba_k, P,  64, N, 64, 0);
      gemm_kernel<64, true, true><<<dim3(NB, 1), B, 0, stream>>>(Ain, 192, Wq, 64, zer,  Qb, 64, N, 64, 0);
    }
    hipMemsetAsync(stE, 0, 256 * 4, stream);           // clears BN1+BN2 stat slots
    passA_kernel<<<GW, B, 0, stream>>>(P, Qb, ssrc, rowo, stE, N);
    fold_kernel<<<1, B, 0, stream>>>(stE, Einv, ga_k, bea_k, Wb_k, bb_k, W2, b2, 64, 64);
    passBC_kernel<<<GW, B, 0, stream>>>(P, Qb, ssrc, rowo, W2, b2, agg, stE2, N);
    fixup_kernel<<<cdiv(N * 64, 256), B, 0, stream>>>(agg, deg, stE2, Einv, gb_k, beb_k,
                                                      xcat + (size_t)k * 64, 192, N);
  }

  // node MLP
  gemm_kernel<64, true, true><<<dim3(NB, 4), B, 0, stream>>>(xcat, 192, pf + hoff[17], 256,
                                                             pf + hoff[18], u_l, 256, N, 192, 1);
  hipMemsetAsync(stN, 0, 512 * 4, stream);
  statsN_kernel<256><<<2048, B, 0, stream>>>(u_l, stN, N);
  fold_kernel<<<1, B, 0, stream>>>(stN, 1.f / (float)N, pf + hoff[19], pf + hoff[20],
                                   pf + hoff[21], pf + hoff[22], Wm1F, bm1F, 256, 64);
  gemm_kernel<64, true, true><<<dim3(NB, 1), B, 0, stream>>>(u_l, 256, Wm1F, 64, bm1F, u1, 64, N, 256, 1);
  hipMemsetAsync(stN, 0, 128 * 4, stream);
  statsN_kernel<64><<<2048, B, 0, stream>>>(u1, stN, N);
  fold_kernel<<<1, B, 0, stream>>>(stN, 1.f / (float)N, pf + hoff[23], pf + hoff[24],
                                   pf + hoff[25], pf + hoff[26], Wm2F, bm2F, 64, 32);
  gemm_kernel<32, true, true><<<dim3(NB, 1), B, 0, stream>>>(u1, 64, Wm2F, 32, bm2F, u2, 32, N, 64, 1);
  hipMemsetAsync(stN, 0, 64 * 4, stream);
  statsN_kernel<32><<<2048, B, 0, stream>>>(u2, stN, N);
  fold_kernel<<<1, B, 0, stream>>>(stN, 1.f / (float)N, pf + hoff[27], pf + hoff[28],
                                   pf + hoff[29], pf + hoff[30], WoF, boF, 32, 24);
  head_kernel<<<cdiv(N, 256), B, 0, stream>>>(u2, WoF, boF, d_out, N, flag);
}

// Round 7
// 2254.666 us; speedup vs baseline: 1.7871x; 1.1361x over previous
//
#include <hip/hip_runtime.h>
#include <hip/hip_bf16.h>

#define EPS 1e-5f
typedef unsigned short bfr;   // raw bf16 bits
typedef unsigned short hfr;   // raw f16 bits
typedef _Float16 h2v __attribute__((ext_vector_type(2)));

#if defined(__has_builtin)
#if __has_builtin(__builtin_amdgcn_fdot2)
#define HAS_FDOT2 1
#endif
#endif

static inline int cdiv(int a, int b){ return (a + b - 1) / b; }

__device__ __forceinline__ float bf2f(bfr u){ return __uint_as_float((unsigned)u << 16); }
__device__ __forceinline__ bfr f2bf(float f){
  unsigned u = __float_as_uint(f);
  u += 0x7fffu + ((u >> 16) & 1u);
  return (bfr)(u >> 16);
}
__device__ __forceinline__ unsigned pack2bf(float a, float b){
  return (unsigned)f2bf(a) | ((unsigned)f2bf(b) << 16);
}
__device__ __forceinline__ float h2f(hfr u){ _Float16 h; __builtin_memcpy(&h, &u, 2); return (float)h; }
__device__ __forceinline__ _Float16 asH(hfr u){ _Float16 h; __builtin_memcpy(&h, &u, 2); return h; }
__device__ __forceinline__ hfr bitsH(_Float16 h){ hfr u; __builtin_memcpy(&u, &h, 2); return u; }
__device__ __forceinline__ hfr f2h(float f){ return bitsH((_Float16)f); }
__device__ __forceinline__ unsigned pack2h(float a, float b){
  return (unsigned)f2h(a) | ((unsigned)f2h(b) << 16);
}
__device__ __forceinline__ h2v u2h2(unsigned u){ h2v r; __builtin_memcpy(&r, &u, 4); return r; }
__device__ __forceinline__ float dot2(h2v a, h2v b, float c){
#ifdef HAS_FDOT2
  return __builtin_amdgcn_fdot2(a, b, c, false);
#else
  return c + (float)a.x * (float)b.x + (float)a.y * (float)b.y;
#endif
}

// ---------------- dtype detection (bf16 vs f32 inputs) ----------------
__global__ __launch_bounds__(256) void detect_kernel(const bfr* __restrict__ xr, int nwords, int* __restrict__ flag){
  int i = threadIdx.x;
  int bad = 0;
  if (i < nwords){
    bfr lo = xr[2 * i];
    int e = (lo >> 7) & 0xFF;
    bool plausible = ((lo & 0x7FFF) == 0) || (e >= 97 && e <= 157);
    bad = plausible ? 0 : 1;
  }
  __shared__ int s[256];
  s[threadIdx.x] = bad; __syncthreads();
  for (int st = 128; st; st >>= 1){
    if (threadIdx.x < st) s[threadIdx.x] += s[threadIdx.x + st];
    __syncthreads();
  }
  if (threadIdx.x == 0) *flag = (s[0] > 32) ? 1 : 0;
}

// ---------------- batched adaptive convert ----------------
#define NPAR 31
struct ParamPtrs { const void* p[NPAR]; };
struct ParamOfs  { int off[NPAR + 1]; };

__global__ __launch_bounds__(256) void acvt_batch_kernel(ParamPtrs pp, ParamOfs po,
                                                         float* __restrict__ out, int total,
                                                         const int* __restrict__ flag){
  int g = blockIdx.x * 256 + threadIdx.x;
  if (g >= total) return;
  int isf = *flag;
  int t = 0;
  while (po.off[t + 1] <= g) ++t;
  int i = g - po.off[t];
  out[g] = isf ? ((const float*)pp.p[t])[i] : bf2f(((const bfr*)pp.p[t])[i]);
}

// ---------------- counting sort of edges by dst ----------------
__global__ __launch_bounds__(256) void deg_kernel(const int* __restrict__ dst, int* __restrict__ deg, int E){
  int e = blockIdx.x * 256 + threadIdx.x;
  if (e < E) atomicAdd(&deg[dst[e]], 1);
}

__global__ __launch_bounds__(256) void scan_kernel(const int* __restrict__ deg, int* __restrict__ row_off,
                                                   int* __restrict__ cur, int N){
  __shared__ int bs[256];
  const int T = 256;
  int chunk = (N + T - 1) / T;
  int t = threadIdx.x;
  int lo = t * chunk, hi = min(lo + chunk, N);
  int s = 0;
  for (int i = lo; i < hi; ++i) s += deg[i];
  bs[t] = s; __syncthreads();
  for (int st = 1; st < T; st <<= 1){
    int v = (t >= st) ? bs[t - st] : 0;
    __syncthreads();
    bs[t] += v;
    __syncthreads();
  }
  int base = (t == 0) ? 0 : bs[t - 1];
  for (int i = lo; i < hi; ++i){
    row_off[i] = base; cur[i] = base;
    base += deg[i];
  }
  if (t == T - 1) row_off[N] = base;
}

__global__ __launch_bounds__(256) void scatter_kernel(const int* __restrict__ src, const int* __restrict__ dst,
                                                      int* __restrict__ cur, int* __restrict__ ssrc, int E){
  int e = blockIdx.x * 256 + threadIdx.x;
  if (e < E){
    int p = atomicAdd(&cur[dst[e]], 1);
    ssrc[p] = src[e];
  }
}

// ---------------- fused P/Q GEMM: y=0 -> P = A@(Wtop-Wbot)+ba ; y=1 -> Q = A@Wbot ----------------
template<bool FIRST>
__global__ __launch_bounds__(256) void gemmPQ_kernel(const void* __restrict__ Av, int lda,
                                                     const float* __restrict__ Wa, int d,
                                                     const float* __restrict__ ba,
                                                     hfr* __restrict__ P, hfr* __restrict__ Q, int N){
  __shared__ float Ws[64 * 64];
  const int y = blockIdx.y;
  const int tot = d * 64;
  for (int i = threadIdx.x; i < tot; i += 256)
    Ws[i] = y ? Wa[tot + i] : (Wa[i] - Wa[tot + i]);
  __syncthreads();
  const int row = blockIdx.x * 256 + threadIdx.x;
  if (row >= N) return;
  float acc[64];
#pragma unroll
  for (int c = 0; c < 64; ++c) acc[c] = 0.f;
  if (FIRST){
    const float* Af = (const float*)Av + (size_t)row * lda;
    for (int k = 0; k < d; ++k){
      float a = Af[k];
      const float* wr = Ws + k * 64;
#pragma unroll
      for (int c4 = 0; c4 < 16; ++c4){
        float4 w = *(const float4*)(wr + 4 * c4);
        acc[4*c4+0] += a * w.x; acc[4*c4+1] += a * w.y;
        acc[4*c4+2] += a * w.z; acc[4*c4+3] += a * w.w;
      }
    }
  } else {
    const hfr* Ah = (const hfr*)Av + (size_t)row * lda;
#pragma unroll
    for (int k8 = 0; k8 < 8; ++k8){
      uint4 av = *(const uint4*)(Ah + k8 * 8);   // 8 f16
      float a[8];
      a[0] = (float)asH((hfr)(av.x & 0xffff)); a[1] = (float)asH((hfr)(av.x >> 16));
      a[2] = (float)asH((hfr)(av.y & 0xffff)); a[3] = (float)asH((hfr)(av.y >> 16));
      a[4] = (float)asH((hfr)(av.z & 0xffff)); a[5] = (float)asH((hfr)(av.z >> 16));
      a[6] = (float)asH((hfr)(av.w & 0xffff)); a[7] = (float)asH((hfr)(av.w >> 16));
#pragma unroll
      for (int kk = 0; kk < 8; ++kk){
        const float* wr = Ws + (k8 * 8 + kk) * 64;
        float ak = a[kk];
#pragma unroll
        for (int c4 = 0; c4 < 16; ++c4){
          float4 w = *(const float4*)(wr + 4 * c4);
          acc[4*c4+0] += ak * w.x; acc[4*c4+1] += ak * w.y;
          acc[4*c4+2] += ak * w.z; acc[4*c4+3] += ak * w.w;
        }
      }
    }
  }
  if (!y){
#pragma unroll
    for (int c = 0; c < 64; ++c) acc[c] += ba[c];
  }
  unsigned p[32];
#pragma unroll
  for (int c = 0; c < 64; c += 2) p[c / 2] = pack2h(acc[c], acc[c + 1]);
  hfr* outp = (y ? Q : P) + (size_t)row * 64;
  uint4* op = (uint4*)outp;
#pragma unroll
  for (int i = 0; i < 8; ++i) op[i] = make_uint4(p[4*i], p[4*i+1], p[4*i+2], p[4*i+3]);
}

// ---------------- generic row-per-thread GEMM (MLP; A f16, K multiple of 64) ----------------
template<int NOUT, bool OHF>
__global__ __launch_bounds__(256) void gemm_kernel(const hfr* __restrict__ Ah, int lda,
                                                   const float* __restrict__ W, int ldw,
                                                   const float* __restrict__ bias,
                                                   void* __restrict__ Ov, int ldo,
                                                   int nrows, int K, int relu){
  __shared__ float Ws[64 * NOUT];
  const int ct = blockIdx.y * NOUT;
  const int row = blockIdx.x * 256 + threadIdx.x;
  float acc[NOUT];
#pragma unroll
  for (int c = 0; c < NOUT; ++c) acc[c] = 0.f;
  for (int k0 = 0; k0 < K; k0 += 64){
    int tot = 64 * NOUT;
    for (int i = threadIdx.x; i < tot; i += 256){
      int kk = i / NOUT, cc = i - kk * NOUT;
      Ws[i] = W[(size_t)(k0 + kk) * ldw + ct + cc];
    }
    __syncthreads();
    if (row < nrows){
      const hfr* Ap = Ah + (size_t)row * lda + k0;
#pragma unroll
      for (int k8 = 0; k8 < 8; ++k8){
        uint4 av = *(const uint4*)(Ap + k8 * 8);
        float a[8];
        a[0] = (float)asH((hfr)(av.x & 0xffff)); a[1] = (float)asH((hfr)(av.x >> 16));
        a[2] = (float)asH((hfr)(av.y & 0xffff)); a[3] = (float)asH((hfr)(av.y >> 16));
        a[4] = (float)asH((hfr)(av.z & 0xffff)); a[5] = (float)asH((hfr)(av.z >> 16));
        a[6] = (float)asH((hfr)(av.w & 0xffff)); a[7] = (float)asH((hfr)(av.w >> 16));
#pragma unroll
        for (int kk = 0; kk < 8; ++kk){
          float ak = a[kk];
          const float* wr = Ws + (k8 * 8 + kk) * NOUT;
#pragma unroll
          for (int c = 0; c < NOUT; ++c) acc[c] += ak * wr[c];
        }
      }
    }
    __syncthreads();
  }
  if (row >= nrows) return;
#pragma unroll
  for (int c = 0; c < NOUT; ++c){
    float v = acc[c] + bias[ct + c];
    acc[c] = relu ? fmaxf(v, 0.f) : v;
  }
  if (OHF){
    unsigned p[NOUT / 2];
#pragma unroll
    for (int c = 0; c < NOUT; c += 2) p[c / 2] = pack2h(acc[c], acc[c + 1]);
    uint4* op = (uint4*)((hfr*)Ov + (size_t)row * ldo + ct);
#pragma unroll
    for (int i = 0; i < NOUT / 8; ++i) op[i] = make_uint4(p[4*i], p[4*i+1], p[4*i+2], p[4*i+3]);
  } else {
    float4* op = (float4*)((float*)Ov + (size_t)row * ldo + ct);
#pragma unroll
    for (int i = 0; i < NOUT / 4; ++i) op[i] = make_float4(acc[4*i], acc[4*i+1], acc[4*i+2], acc[4*i+3]);
  }
}

// ---------------- passA (sorted, 8-edge unrolled batches): BN1 stats of relu_f16(P[n]+Q[src]) ----------------
__global__ __launch_bounds__(256) void passA_kernel(const hfr* __restrict__ P, const hfr* __restrict__ Q,
                                                    const int* __restrict__ ssrc, const int* __restrict__ row_off,
                                                    float* __restrict__ stats, int N){
  const int lane = threadIdx.x & 63;
  const int wid = (blockIdx.x * 256 + threadIdx.x) >> 6;
  const int nw = (gridDim.x * 256) >> 6;
  const _Float16 z16 = (_Float16)0;
  float sum = 0.f, sq = 0.f;
  for (int n = wid; n < N; n += nw){
    _Float16 pn = asH(P[(size_t)n * 64 + lane]);
    const int e0 = row_off[n], e1 = row_off[n + 1];
    const int lim = e1 - 1;
    for (int eb = e0; eb < e1; eb += 8){
      int sv = ssrc[min(eb + (lane & 7), lim)];   // one vector load for 8 edge srcs
#pragma unroll
      for (int j = 0; j < 8; ++j){
        int sj = __shfl(sv, j, 64);
        _Float16 a = pn + asH(Q[(size_t)sj * 64 + lane]);
        float v = (a < z16) ? 0.f : (float)a;
        bool valid = (eb + j) < e1;
        sum += valid ? v : 0.f;
        sq  += valid ? v * v : 0.f;
      }
    }
  }
  atomicAdd(&stats[lane], sum);
  atomicAdd(&stats[64 + lane], sq);
}

// ---------------- fold BN(stats,g,be) into next Lin ----------------
__global__ __launch_bounds__(256) void fold_kernel(const float* __restrict__ stats, float cntInv,
                                                   const float* __restrict__ g, const float* __restrict__ be,
                                                   const float* __restrict__ Wn, const float* __restrict__ bn,
                                                   float* __restrict__ Wo, float* __restrict__ bo, int K, int C){
  __shared__ float a[256], bb[256], bsum[256];
  for (int k = threadIdx.x; k < K; k += 256){
    float mu = stats[k] * cntInv;
    float var = stats[K + k] * cntInv - mu * mu;
    float ai = g[k] * rsqrtf(var + EPS);
    a[k] = ai; bb[k] = be[k] - ai * mu;
  }
  __syncthreads();
  int tot = K * C;
  for (int i = threadIdx.x; i < tot; i += 256) Wo[i] = a[i / C] * Wn[i];
  int parts = 256 / C; if (parts < 1) parts = 1;
  int c = threadIdx.x % C, p = threadIdx.x / C;
  float s = 0.f;
  if (p < parts){
    for (int k = p; k < K; k += parts) s += bb[k] * Wn[(size_t)k * C + c];
    bsum[p * C + c] = s;
  }
  __syncthreads();
  if (threadIdx.x < C){
    float t = bn[threadIdx.x];
    for (int pp = 0; pp < parts; ++pp) t += bsum[pp * C + threadIdx.x];
    bo[threadIdx.x] = t;
  }
}

// ---------------- passBC (sorted, 8-edge unrolled batches): dot2 GEMM + BN2 stats + register max ----------------
__global__ __launch_bounds__(256) void passBC_kernel(const hfr* __restrict__ P, const hfr* __restrict__ Q,
                                                     const int* __restrict__ ssrc, const int* __restrict__ row_off,
                                                     const float* __restrict__ W2, const float* __restrict__ b2,
                                                     float* __restrict__ agg, float* __restrict__ stats, int N){
  __shared__ hfr ht[4][8][64];     // 4 KB: per-wave staging of 8 h1 rows (f16)
  const int lane = threadIdx.x & 63;
  const int wib = threadIdx.x >> 6;
  const int wid = (blockIdx.x * 256 + threadIdx.x) >> 6;
  const int nw = (gridDim.x * 256) >> 6;
  const _Float16 z16 = (_Float16)0;
  h2v Wh[32];
#pragma unroll
  for (int k2 = 0; k2 < 32; ++k2){
    h2v w; w.x = (_Float16)W2[(2 * k2) * 64 + lane]; w.y = (_Float16)W2[(2 * k2 + 1) * 64 + lane];
    Wh[k2] = w;
  }
  const float bc = b2[lane];
  hfr (*hl)[64] = ht[wib];
  float sum = 0.f, sq = 0.f;
  for (int n = wid; n < N; n += nw){
    _Float16 pn = asH(P[(size_t)n * 64 + lane]);
    const int e0 = row_off[n], e1 = row_off[n + 1];
    const int lim = e1 - 1;
    float mx = 0.f;
    for (int eb = e0; eb < e1; eb += 8){
      int sv = ssrc[min(eb + (lane & 7), lim)];
#pragma unroll
      for (int j = 0; j < 8; ++j){                 // 8 independent gathers in flight
        int sj = __shfl(sv, j, 64);
        _Float16 s = pn + asH(Q[(size_t)sj * 64 + lane]);
        hl[j][lane] = bitsH((s < z16) ? z16 : s);
      }
      // intra-wave LDS dependency: compiler inserts lgkmcnt waits, no barrier needed
#pragma unroll
      for (int j = 0; j < 8; ++j){                 // 8 interleaved dot2 chains
        const uint4* hp = (const uint4*)hl[j];
        float acc = bc;
#pragma unroll
        for (int r = 0; r < 8; ++r){
          uint4 hv = hp[r];                        // 8 f16 = 4 pairs
          acc = dot2(u2h2(hv.x), Wh[4*r+0], acc);
          acc = dot2(u2h2(hv.y), Wh[4*r+1], acc);
          acc = dot2(u2h2(hv.z), Wh[4*r+2], acc);
          acc = dot2(u2h2(hv.w), Wh[4*r+3], acc);
        }
        float v = fmaxf(acc, 0.f);
        mx = fmaxf(mx, v);                          // clamped dup edges: same value, harmless
        bool valid = (eb + j) < e1;
        sum += valid ? v : 0.f;
        sq  += valid ? v * v : 0.f;
      }
    }
    agg[(size_t)n * 64 + lane] = mx;
  }
  atomicAdd(&stats[lane], sum);
  atomicAdd(&stats[64 + lane], sq);
}

// ---------------- fixup with inlined BN2 coefficients ----------------
__global__ __launch_bounds__(256) void fixup_kernel(const float* __restrict__ agg, const int* __restrict__ deg,
                                                    const float* __restrict__ stats, float cntInv,
                                                    const float* __restrict__ g, const float* __restrict__ be,
                                                    hfr* __restrict__ xout, int ldx, int N){
  int t = blockIdx.x * 256 + threadIdx.x;
  if (t >= N * 64) return;
  int n = t >> 6, c = t & 63;
  float mu = stats[c] * cntInv;
  float var = stats[64 + c] * cntInv - mu * mu;
  float a = g[c] * rsqrtf(var + EPS);
  float b = be[c] - a * mu;
  float v = 0.f;
  if (deg[n] > 0) v = a * agg[t] + b;
  xout[(size_t)n * ldx + c] = f2h(v);
}

// ---------------- node BN stats over f16 activations ----------------
template<int C>
__global__ __launch_bounds__(256) void statsN_kernel(const hfr* __restrict__ u, float* __restrict__ stats, int N){
  constexpr int RP = 256 / C;
  const int c = threadIdx.x % C, j = threadIdx.x / C;
  float sum = 0.f, sq = 0.f;
  for (int r = blockIdx.x * RP + j; r < N; r += gridDim.x * RP){
    float v = h2f(u[(size_t)r * C + c]);
    sum += v; sq += v * v;
  }
  __shared__ float ls[256], lq[256];
  ls[threadIdx.x] = sum; lq[threadIdx.x] = sq;
  __syncthreads();
  if (threadIdx.x < C){
    float s = 0.f, q = 0.f;
#pragma unroll
    for (int jj = 0; jj < RP; ++jj){ s += ls[jj * C + c]; q += lq[jj * C + c]; }
    atomicAdd(&stats[c], s); atomicAdd(&stats[C + c], q);
  }
}

// ---------------- head: logits + log_softmax ----------------
__global__ __launch_bounds__(256) void head_kernel(const hfr* __restrict__ u2,
                                                   const float* __restrict__ Wo, const float* __restrict__ bo,
                                                   void* __restrict__ out, int N, const int* __restrict__ flag){
  __shared__ float Ws[32 * 24];
  __shared__ float bs[24];
  for (int i = threadIdx.x; i < 32 * 24; i += 256) Ws[i] = Wo[i];
  if (threadIdx.x < 24) bs[threadIdx.x] = bo[threadIdx.x];
  __syncthreads();
  int r = blockIdx.x * 256 + threadIdx.x;
  if (r >= N) return;
  int isf = *flag;
  float l[24];
#pragma unroll
  for (int c = 0; c < 24; ++c) l[c] = bs[c];
  const hfr* up = u2 + (size_t)r * 32;
#pragma unroll
  for (int k = 0; k < 32; ++k){
    float v = h2f(up[k]);
#pragma unroll
    for (int c = 0; c < 24; ++c) l[c] += v * Ws[k * 24 + c];
  }
  float m = l[0];
#pragma unroll
  for (int c = 1; c < 24; ++c) m = fmaxf(m, l[c]);
  float s = 0.f;
#pragma unroll
  for (int c = 0; c < 24; ++c) s += expf(l[c] - m);
  float lse = m + logf(s);
  if (isf){
    float4* op = (float4*)((float*)out + (size_t)r * 24);
#pragma unroll
    for (int i = 0; i < 6; ++i)
      op[i] = make_float4(l[4*i] - lse, l[4*i+1] - lse, l[4*i+2] - lse, l[4*i+3] - lse);
  } else {
    unsigned p[12];
#pragma unroll
    for (int c = 0; c < 24; c += 2) p[c / 2] = pack2bf(l[c] - lse, l[c + 1] - lse);
    uint4* op = (uint4*)((bfr*)out + (size_t)r * 24);
#pragma unroll
    for (int i = 0; i < 3; ++i) op[i] = make_uint4(p[4*i], p[4*i+1], p[4*i+2], p[4*i+3]);
  }
}

// ---------------- host ----------------
// Footprint ~51 MB (ws-safe since round 3). Aliases disjoint in time:
// u_l over P+Q+agg (dead after conv loop); u1/u2 over xcat (dead after lin1).
extern "C" void kernel_launch(void* const* d_in, const int* in_sizes, int n_in,
                              void* d_out, int out_size, void* d_ws, size_t ws_size,
                              hipStream_t stream){
  const int N = in_sizes[0] / 6;
  const int E = in_sizes[31] / 2;
  const int* edge = (const int*)d_in[31];
  const int* src = edge;
  const int* dst = edge + E;

  size_t off = 0; char* basep = (char*)d_ws;
  auto alloc = [&](size_t bytes) -> void* {
    void* p = basep + off;
    off = (off + bytes + 255) & ~(size_t)255;
    return p;
  };
  float* W2   = (float*)alloc(64 * 64 * 4);
  float* b2   = (float*)alloc(64 * 4);
  float* Wm1F = (float*)alloc(256 * 64 * 4);
  float* bm1F = (float*)alloc(64 * 4);
  float* Wm2F = (float*)alloc(64 * 32 * 4);
  float* bm2F = (float*)alloc(32 * 4);
  float* WoF  = (float*)alloc(32 * 24 * 4);
  float* boF  = (float*)alloc(24 * 4);
  float* stE  = (float*)alloc(256 * 4);     // [0:128) BN1 stats, [128:256) BN2 stats
  float* stE2 = stE + 128;
  float* stN  = (float*)alloc(512 * 4);
  int*   flag = (int*)  alloc(4);
  int*   deg  = (int*)  alloc((size_t)N * 4);
  int*   rowo = (int*)  alloc((size_t)(N + 1) * 4);
  int*   cur  = (int*)  alloc((size_t)N * 4);
  int*   ssrc = (int*)  alloc((size_t)E * 4);

  ParamPtrs pp; ParamOfs po;
  int hoff[32]; int total = 0;
  for (int s = 0; s < NPAR; ++s){
    int idx = (s < 30) ? (s + 1) : 0;
    pp.p[s] = d_in[idx];
    po.off[s] = total;
    hoff[idx] = total;
    total += in_sizes[idx];
  }
  po.off[NPAR] = total;
  float* pf = (float*)alloc((size_t)total * 4);

  hfr*   P    = (hfr*)  alloc((size_t)N * 64 * 2);
  hfr*   Qb   = (hfr*)  alloc((size_t)N * 64 * 2);
  float* agg  = (float*)alloc((size_t)N * 64 * 4);
  hfr*   xcat = (hfr*)  alloc((size_t)N * 192 * 2);
  hfr* u_l = (hfr*)P;                 // [N,256] f16 over P+Q+agg
  hfr* u1  = xcat;                    // [N,64]  f16
  hfr* u2  = xcat + (size_t)N * 64;   // [N,32]  f16
  (void)ws_size; (void)n_in; (void)out_size;

  dim3 B(256);
  detect_kernel<<<1, B, 0, stream>>>((const bfr*)d_in[0], 256, flag);
  acvt_batch_kernel<<<cdiv(total, 256), B, 0, stream>>>(pp, po, pf, total, flag);

  hipMemsetAsync(deg, 0, (size_t)N * 4, stream);
  deg_kernel<<<cdiv(E, 256), B, 0, stream>>>(dst, deg, E);
  scan_kernel<<<1, B, 0, stream>>>(deg, rowo, cur, N);
  scatter_kernel<<<cdiv(E, 256), B, 0, stream>>>(src, dst, cur, ssrc, E);

  const int NB = cdiv(N, 256);
  const int GW = 2048;
  const float Einv = 1.f / (float)E;
  for (int k = 0; k < 3; ++k){
    const float *Wa_k, *ba_k, *ga_k, *bea_k, *Wb_k, *bb_k, *gb_k, *beb_k;
    if (k == 0){
      Wa_k = pf + hoff[1]; ba_k = pf + hoff[2]; ga_k = pf + hoff[3]; bea_k = pf + hoff[4];
      Wb_k = pf + hoff[5]; bb_k = pf + hoff[6]; gb_k = pf + hoff[7]; beb_k = pf + hoff[8];
    } else {
      int kk = k - 1;
      Wa_k = pf + hoff[9]  + (size_t)kk * 128 * 64;
      ba_k = pf + hoff[10] + kk * 64;
      ga_k = pf + hoff[11] + kk * 64;
      bea_k= pf + hoff[12] + kk * 64;
      Wb_k = pf + hoff[13] + (size_t)kk * 64 * 64;
      bb_k = pf + hoff[14] + kk * 64;
      gb_k = pf + hoff[15] + kk * 64;
      beb_k= pf + hoff[16] + kk * 64;
    }
    if (k == 0)
      gemmPQ_kernel<true><<<dim3(NB, 2), B, 0, stream>>>(pf + hoff[0], 6, Wa_k, 6, ba_k, P, Qb, N);
    else
      gemmPQ_kernel<false><<<dim3(NB, 2), B, 0, stream>>>(xcat + (size_t)(k - 1) * 64, 192, Wa_k, 64, ba_k, P, Qb, N);
    hipMemsetAsync(stE, 0, 256 * 4, stream);
    passA_kernel<<<GW, B, 0, stream>>>(P, Qb, ssrc, rowo, stE, N);
    fold_kernel<<<1, B, 0, stream>>>(stE, Einv, ga_k, bea_k, Wb_k, bb_k, W2, b2, 64, 64);
    passBC_kernel<<<GW, B, 0, stream>>>(P, Qb, ssrc, rowo, W2, b2, agg, stE2, N);
    fixup_kernel<<<cdiv(N * 64, 256), B, 0, stream>>>(agg, deg, stE2, Einv, gb_k, beb_k,
                                                      xcat + (size_t)k * 64, 192, N);
  }

  // node MLP
  gemm_kernel<64, true><<<dim3(NB, 4), B, 0, stream>>>(xcat, 192, pf + hoff[17], 256,
                                                       pf + hoff[18], u_l, 256, N, 192, 1);
  hipMemsetAsync(stN, 0, 512 * 4, stream);
  statsN_kernel<256><<<2048, B, 0, stream>>>(u_l, stN, N);
  fold_kernel<<<1, B, 0, stream>>>(stN, 1.f / (float)N, pf + hoff[19], pf + hoff[20],
                                   pf + hoff[21], pf + hoff[22], Wm1F, bm1F, 256, 64);
  gemm_kernel<64, true><<<dim3(NB, 1), B, 0, stream>>>(u_l, 256, Wm1F, 64, bm1F, u1, 64, N, 256, 1);
  hipMemsetAsync(stN, 0, 128 * 4, stream);
  statsN_kernel<64><<<2048, B, 0, stream>>>(u1, stN, N);
  fold_kernel<<<1, B, 0, stream>>>(stN, 1.f / (float)N, pf + hoff[23], pf + hoff[24],
                                   pf + hoff[25], pf + hoff[26], Wm2F, bm2F, 64, 32);
  gemm_kernel<32, true><<<dim3(NB, 1), B, 0, stream>>>(u1, 64, Wm2F, 32, bm2F, u2, 32, N, 64, 1);
  hipMemsetAsync(stN, 0, 64 * 4, stream);
  statsN_kernel<32><<<2048, B, 0, stream>>>(u2, stN, N);
  fold_kernel<<<1, B, 0, stream>>>(stN, 1.f / (float)N, pf + hoff[27], pf + hoff[28],
                                   pf + hoff[29], pf + hoff[30], WoF, boF, 32, 24);
  head_kernel<<<cdiv(N, 256), B, 0, stream>>>(u2, WoF, boF, d_out, N, flag);
}

// Round 8
// 1998.093 us; speedup vs baseline: 2.0166x; 1.1284x over previous
//
#include <hip/hip_runtime.h>
#include <hip/hip_bf16.h>

#define EPS 1e-5f
typedef unsigned short bfr;   // raw bf16 bits
typedef unsigned short hfr;   // raw f16 bits
typedef _Float16 h2v __attribute__((ext_vector_type(2)));
typedef _Float16 f16x8 __attribute__((ext_vector_type(8)));
typedef float f32x4 __attribute__((ext_vector_type(4)));

#if defined(__has_builtin)
#if __has_builtin(__builtin_amdgcn_fdot2)
#define HAS_FDOT2 1
#endif
#endif

static inline int cdiv(int a, int b){ return (a + b - 1) / b; }

__device__ __forceinline__ float bf2f(bfr u){ return __uint_as_float((unsigned)u << 16); }
__device__ __forceinline__ bfr f2bf(float f){
  unsigned u = __float_as_uint(f);
  u += 0x7fffu + ((u >> 16) & 1u);
  return (bfr)(u >> 16);
}
__device__ __forceinline__ unsigned pack2bf(float a, float b){
  return (unsigned)f2bf(a) | ((unsigned)f2bf(b) << 16);
}
__device__ __forceinline__ float h2f(hfr u){ _Float16 h; __builtin_memcpy(&h, &u, 2); return (float)h; }
__device__ __forceinline__ _Float16 asH(hfr u){ _Float16 h; __builtin_memcpy(&h, &u, 2); return h; }
__device__ __forceinline__ hfr bitsH(_Float16 h){ hfr u; __builtin_memcpy(&u, &h, 2); return u; }
__device__ __forceinline__ hfr f2h(float f){ return bitsH((_Float16)f); }
__device__ __forceinline__ unsigned pack2h(float a, float b){
  return (unsigned)f2h(a) | ((unsigned)f2h(b) << 16);
}
__device__ __forceinline__ h2v u2h2(unsigned u){ h2v r; __builtin_memcpy(&r, &u, 4); return r; }
__device__ __forceinline__ float dot2(h2v a, h2v b, float c){
#ifdef HAS_FDOT2
  return __builtin_amdgcn_fdot2(a, b, c, false);
#else
  return c + (float)a.x * (float)b.x + (float)a.y * (float)b.y;
#endif
}

// ---------------- dtype detection (bf16 vs f32 inputs) ----------------
__global__ __launch_bounds__(256) void detect_kernel(const bfr* __restrict__ xr, int nwords, int* __restrict__ flag){
  int i = threadIdx.x;
  int bad = 0;
  if (i < nwords){
    bfr lo = xr[2 * i];
    int e = (lo >> 7) & 0xFF;
    bool plausible = ((lo & 0x7FFF) == 0) || (e >= 97 && e <= 157);
    bad = plausible ? 0 : 1;
  }
  __shared__ int s[256];
  s[threadIdx.x] = bad; __syncthreads();
  for (int st = 128; st; st >>= 1){
    if (threadIdx.x < st) s[threadIdx.x] += s[threadIdx.x + st];
    __syncthreads();
  }
  if (threadIdx.x == 0) *flag = (s[0] > 32) ? 1 : 0;
}

// ---------------- batched adaptive convert ----------------
#define NPAR 31
struct ParamPtrs { const void* p[NPAR]; };
struct ParamOfs  { int off[NPAR + 1]; };

__global__ __launch_bounds__(256) void acvt_batch_kernel(ParamPtrs pp, ParamOfs po,
                                                         float* __restrict__ out, int total,
                                                         const int* __restrict__ flag){
  int g = blockIdx.x * 256 + threadIdx.x;
  if (g >= total) return;
  int isf = *flag;
  int t = 0;
  while (po.off[t + 1] <= g) ++t;
  int i = g - po.off[t];
  out[g] = isf ? ((const float*)pp.p[t])[i] : bf2f(((const bfr*)pp.p[t])[i]);
}

// ---------------- counting sort of edges by dst ----------------
__global__ __launch_bounds__(256) void deg_kernel(const int* __restrict__ dst, int* __restrict__ deg, int E){
  int e = blockIdx.x * 256 + threadIdx.x;
  if (e < E) atomicAdd(&deg[dst[e]], 1);
}

__global__ __launch_bounds__(256) void scan_kernel(const int* __restrict__ deg, int* __restrict__ row_off,
                                                   int* __restrict__ cur, int N){
  __shared__ int bs[256];
  const int T = 256;
  int chunk = (N + T - 1) / T;
  int t = threadIdx.x;
  int lo = t * chunk, hi = min(lo + chunk, N);
  int s = 0;
  for (int i = lo; i < hi; ++i) s += deg[i];
  bs[t] = s; __syncthreads();
  for (int st = 1; st < T; st <<= 1){
    int v = (t >= st) ? bs[t - st] : 0;
    __syncthreads();
    bs[t] += v;
    __syncthreads();
  }
  int base = (t == 0) ? 0 : bs[t - 1];
  for (int i = lo; i < hi; ++i){
    row_off[i] = base; cur[i] = base;
    base += deg[i];
  }
  if (t == T - 1) row_off[N] = base;
}

__global__ __launch_bounds__(256) void scatter_kernel(const int* __restrict__ src, const int* __restrict__ dst,
                                                      int* __restrict__ cur, int* __restrict__ ssrc, int E){
  int e = blockIdx.x * 256 + threadIdx.x;
  if (e < E){
    int p = atomicAdd(&cur[dst[e]], 1);
    ssrc[p] = src[e];
  }
}

// ---------------- fused P/Q GEMM: y=0 -> P = A@(Wtop-Wbot)+ba ; y=1 -> Q = A@Wbot ----------------
template<bool FIRST>
__global__ __launch_bounds__(256) void gemmPQ_kernel(const void* __restrict__ Av, int lda,
                                                     const float* __restrict__ Wa, int d,
                                                     const float* __restrict__ ba,
                                                     hfr* __restrict__ P, hfr* __restrict__ Q, int N){
  __shared__ unsigned WsU[64 * 64];    // FIRST: f32 Ws[6*64]; else packed f16 pairs Wp[32*64]
  const int y = blockIdx.y;
  const int tot = d * 64;
  if (FIRST){
    float* Ws = (float*)WsU;
    for (int i = threadIdx.x; i < tot; i += 256)
      Ws[i] = y ? Wa[tot + i] : (Wa[i] - Wa[tot + i]);
  } else {
    for (int i = threadIdx.x; i < 32 * 64; i += 256){
      int p = i >> 6, c = i & 63;
      int i0 = (2 * p) * 64 + c, i1 = (2 * p + 1) * 64 + c;
      float w0 = y ? Wa[tot + i0] : (Wa[i0] - Wa[tot + i0]);
      float w1 = y ? Wa[tot + i1] : (Wa[i1] - Wa[tot + i1]);
      WsU[i] = pack2h(w0, w1);
    }
  }
  __syncthreads();
  const int row = blockIdx.x * 256 + threadIdx.x;
  if (row >= N) return;
  float acc[64];
#pragma unroll
  for (int c = 0; c < 64; ++c) acc[c] = 0.f;
  if (FIRST){
    const float* Ws = (const float*)WsU;
    const float* Af = (const float*)Av + (size_t)row * lda;
    for (int k = 0; k < d; ++k){
      float a = Af[k];
      const float* wr = Ws + k * 64;
#pragma unroll
      for (int c4 = 0; c4 < 16; ++c4){
        float4 w = *(const float4*)(wr + 4 * c4);
        acc[4*c4+0] += a * w.x; acc[4*c4+1] += a * w.y;
        acc[4*c4+2] += a * w.z; acc[4*c4+3] += a * w.w;
      }
    }
  } else {
    const hfr* Ah = (const hfr*)Av + (size_t)row * lda;
#pragma unroll
    for (int k8 = 0; k8 < 8; ++k8){
      uint4 av = *(const uint4*)(Ah + k8 * 8);   // 8 f16 = 4 pairs
      unsigned pr[4] = {av.x, av.y, av.z, av.w};
#pragma unroll
      for (int pi = 0; pi < 4; ++pi){
        h2v ap = u2h2(pr[pi]);
        const unsigned* wr = WsU + (k8 * 4 + pi) * 64;
#pragma unroll
        for (int c = 0; c < 64; ++c) acc[c] = dot2(ap, u2h2(wr[c]), acc[c]);
      }
    }
  }
  if (!y){
#pragma unroll
    for (int c = 0; c < 64; ++c) acc[c] += ba[c];
  }
  unsigned p[32];
#pragma unroll
  for (int c = 0; c < 64; c += 2) p[c / 2] = pack2h(acc[c], acc[c + 1]);
  hfr* outp = (y ? Q : P) + (size_t)row * 64;
  uint4* op = (uint4*)outp;
#pragma unroll
  for (int i = 0; i < 8; ++i) op[i] = make_uint4(p[4*i], p[4*i+1], p[4*i+2], p[4*i+3]);
}

// ---------------- generic row-per-thread GEMM (MLP; A f16, K mult of 64), packed-pair weights ----------------
template<int NOUT, bool OHF>
__global__ __launch_bounds__(256) void gemm_kernel(const hfr* __restrict__ Ah, int lda,
                                                   const float* __restrict__ W, int ldw,
                                                   const float* __restrict__ bias,
                                                   void* __restrict__ Ov, int ldo,
                                                   int nrows, int K, int relu){
  __shared__ unsigned Wp[32 * NOUT];
  const int ct = blockIdx.y * NOUT;
  const int row = blockIdx.x * 256 + threadIdx.x;
  float acc[NOUT];
#pragma unroll
  for (int c = 0; c < NOUT; ++c) acc[c] = 0.f;
  for (int k0 = 0; k0 < K; k0 += 64){
    for (int i = threadIdx.x; i < 32 * NOUT; i += 256){
      int p = i / NOUT, c = i - p * NOUT;
      float w0 = W[(size_t)(k0 + 2 * p) * ldw + ct + c];
      float w1 = W[(size_t)(k0 + 2 * p + 1) * ldw + ct + c];
      Wp[i] = pack2h(w0, w1);
    }
    __syncthreads();
    if (row < nrows){
      const hfr* Ap = Ah + (size_t)row * lda + k0;
#pragma unroll
      for (int k8 = 0; k8 < 8; ++k8){
        uint4 av = *(const uint4*)(Ap + k8 * 8);
        unsigned pr[4] = {av.x, av.y, av.z, av.w};
#pragma unroll
        for (int pi = 0; pi < 4; ++pi){
          h2v ap = u2h2(pr[pi]);
          const unsigned* wr = Wp + (k8 * 4 + pi) * NOUT;
#pragma unroll
          for (int c = 0; c < NOUT; ++c) acc[c] = dot2(ap, u2h2(wr[c]), acc[c]);
        }
      }
    }
    __syncthreads();
  }
  if (row >= nrows) return;
#pragma unroll
  for (int c = 0; c < NOUT; ++c){
    float v = acc[c] + bias[ct + c];
    acc[c] = relu ? fmaxf(v, 0.f) : v;
  }
  if (OHF){
    unsigned p[NOUT / 2];
#pragma unroll
    for (int c = 0; c < NOUT; c += 2) p[c / 2] = pack2h(acc[c], acc[c + 1]);
    uint4* op = (uint4*)((hfr*)Ov + (size_t)row * ldo + ct);
#pragma unroll
    for (int i = 0; i < NOUT / 8; ++i) op[i] = make_uint4(p[4*i], p[4*i+1], p[4*i+2], p[4*i+3]);
  } else {
    float4* op = (float4*)((float*)Ov + (size_t)row * ldo + ct);
#pragma unroll
    for (int i = 0; i < NOUT / 4; ++i) op[i] = make_float4(acc[4*i], acc[4*i+1], acc[4*i+2], acc[4*i+3]);
  }
}

// ---------------- passA (sorted, 16-edge batches): BN1 stats of relu_f16(P[n]+Q[src]) ----------------
__global__ __launch_bounds__(256) void passA_kernel(const hfr* __restrict__ P, const hfr* __restrict__ Q,
                                                    const int* __restrict__ ssrc, const int* __restrict__ row_off,
                                                    float* __restrict__ stats, int N){
  const int lane = threadIdx.x & 63;
  const int wid = (blockIdx.x * 256 + threadIdx.x) >> 6;
  const int nw = (gridDim.x * 256) >> 6;
  const _Float16 z16 = (_Float16)0;
  float sum = 0.f, sq = 0.f;
  for (int n = wid; n < N; n += nw){
    const int e0 = row_off[n], e1 = row_off[n + 1];
    if (e0 >= e1) continue;
    _Float16 pn = asH(P[(size_t)n * 64 + lane]);
    const int lim = e1 - 1;
    for (int eb = e0; eb < e1; eb += 16){
      int sv = ssrc[min(eb + (lane & 15), lim)];
#pragma unroll
      for (int j = 0; j < 16; ++j){
        int sj = __shfl(sv, j, 64);
        _Float16 a = pn + asH(Q[(size_t)sj * 64 + lane]);
        float v = (a < z16) ? 0.f : (float)a;
        bool valid = (eb + j) < e1;
        sum += valid ? v : 0.f;
        sq  += valid ? v * v : 0.f;
      }
    }
  }
  atomicAdd(&stats[lane], sum);
  atomicAdd(&stats[64 + lane], sq);
}

// ---------------- fold BN(stats,g,be) into next Lin ----------------
__global__ __launch_bounds__(256) void fold_kernel(const float* __restrict__ stats, float cntInv,
                                                   const float* __restrict__ g, const float* __restrict__ be,
                                                   const float* __restrict__ Wn, const float* __restrict__ bn,
                                                   float* __restrict__ Wo, float* __restrict__ bo, int K, int C){
  __shared__ float a[256], bb[256], bsum[256];
  for (int k = threadIdx.x; k < K; k += 256){
    float mu = stats[k] * cntInv;
    float var = stats[K + k] * cntInv - mu * mu;
    float ai = g[k] * rsqrtf(var + EPS);
    a[k] = ai; bb[k] = be[k] - ai * mu;
  }
  __syncthreads();
  int tot = K * C;
  for (int i = threadIdx.x; i < tot; i += 256) Wo[i] = a[i / C] * Wn[i];
  int parts = 256 / C; if (parts < 1) parts = 1;
  int c = threadIdx.x % C, p = threadIdx.x / C;
  float s = 0.f;
  if (p < parts){
    for (int k = p; k < K; k += parts) s += bb[k] * Wn[(size_t)k * C + c];
    bsum[p * C + c] = s;
  }
  __syncthreads();
  if (threadIdx.x < C){
    float t = bn[threadIdx.x];
    for (int pp = 0; pp < parts; ++pp) t += bsum[pp * C + threadIdx.x];
    bo[threadIdx.x] = t;
  }
}

// ---------------- passBC (sorted): MFMA 16-edge batches + BN2 stats + register segment-max ----------------
// A[m=lane&15][k=quad*8+j] (verified m120); C[col=lane&15][row=quad*4+reg] (verified m89).
// Rows padded to 72 f16 (144 B) so quad A-frag b128 reads spread banks.
__global__ __launch_bounds__(256) void passBC_kernel(const hfr* __restrict__ P, const hfr* __restrict__ Q,
                                                     const int* __restrict__ ssrc, const int* __restrict__ row_off,
                                                     const float* __restrict__ W2, const float* __restrict__ b2,
                                                     float* __restrict__ agg, float* __restrict__ stats, int N){
  __shared__ _Float16 W2T[64 * 72];     // [c][k] f16 transposed, padded
  __shared__ _Float16 ht[4][16][72];    // per-wave 16-edge h1 tile, padded
  const int tid = threadIdx.x;
  const int lane = tid & 63;
  const int wib = tid >> 6;
  const _Float16 z16 = (_Float16)0;
  for (int i = tid; i < 4096; i += 256){
    int c = i >> 6, k = i & 63;
    W2T[c * 72 + k] = (_Float16)W2[k * 64 + c];
  }
  __syncthreads();
  // B fragments: Bf[t][h] supplies B[k=h*32+quad*8+j][n=t*16+(lane&15)]
  f16x8 Bf[4][2];
#pragma unroll
  for (int t = 0; t < 4; ++t)
#pragma unroll
    for (int h = 0; h < 2; ++h){
      int c = t * 16 + (lane & 15);
      Bf[t][h] = *(const f16x8*)&W2T[c * 72 + h * 32 + (lane >> 4) * 8];
    }
  float bc[4];
#pragma unroll
  for (int t = 0; t < 4; ++t) bc[t] = b2[t * 16 + (lane & 15)];
  _Float16 (*hl)[72] = ht[wib];
  const int wid = (blockIdx.x * 256 + tid) >> 6;
  const int nw = (gridDim.x * 256) >> 6;
  float sumT[4] = {0.f,0.f,0.f,0.f}, sqT[4] = {0.f,0.f,0.f,0.f};
  for (int n = wid; n < N; n += nw){
    const int e0 = row_off[n], e1 = row_off[n + 1];
    if (e0 >= e1) continue;
    _Float16 pn = asH(P[(size_t)n * 64 + lane]);
    const int lim = e1 - 1;
    float mxT[4] = {0.f,0.f,0.f,0.f};
    for (int eb = e0; eb < e1; eb += 16){
      int sv = ssrc[min(eb + (lane & 15), lim)];
#pragma unroll
      for (int j = 0; j < 16; ++j){          // 16 independent gathers in flight
        int sj = __shfl(sv, j, 64);
        _Float16 s = pn + asH(Q[(size_t)sj * 64 + lane]);
        hl[j][lane] = (s < z16) ? z16 : s;
      }
      // intra-wave LDS RAW: compiler emits lgkmcnt wait, no barrier needed
      f16x8 A0 = *(const f16x8*)&hl[lane & 15][(lane >> 4) * 8];
      f16x8 A1 = *(const f16x8*)&hl[lane & 15][32 + (lane >> 4) * 8];
#pragma unroll
      for (int t = 0; t < 4; ++t){
        f32x4 Cv = {bc[t], bc[t], bc[t], bc[t]};
        Cv = __builtin_amdgcn_mfma_f32_16x16x32_f16(A0, Bf[t][0], Cv, 0, 0, 0);
        Cv = __builtin_amdgcn_mfma_f32_16x16x32_f16(A1, Bf[t][1], Cv, 0, 0, 0);
#pragma unroll
        for (int r = 0; r < 4; ++r){
          float v = fmaxf(Cv[r], 0.f);
          int rowi = (lane >> 4) * 4 + r;
          bool valid = (eb + rowi) < e1;
          mxT[t] = fmaxf(mxT[t], v);          // clamped dup rows mirror a real edge: max-safe
          sumT[t] += valid ? v : 0.f;
          sqT[t]  += valid ? v * v : 0.f;
        }
      }
    }
    // combine quads (rows) then store col=lane (t = lane>>4)
#pragma unroll
    for (int t = 0; t < 4; ++t){
      float m = mxT[t];
      m = fmaxf(m, __shfl_xor(m, 16, 64));
      m = fmaxf(m, __shfl_xor(m, 32, 64));
      mxT[t] = m;
    }
    float outv = (lane < 16) ? mxT[0] : (lane < 32) ? mxT[1] : (lane < 48) ? mxT[2] : mxT[3];
    agg[(size_t)n * 64 + lane] = outv;
  }
#pragma unroll
  for (int t = 0; t < 4; ++t){
    float s = sumT[t], q = sqT[t];
    s += __shfl_xor(s, 16, 64); s += __shfl_xor(s, 32, 64);
    q += __shfl_xor(q, 16, 64); q += __shfl_xor(q, 32, 64);
    sumT[t] = s; sqT[t] = q;
  }
  float ssel = (lane < 16) ? sumT[0] : (lane < 32) ? sumT[1] : (lane < 48) ? sumT[2] : sumT[3];
  float qsel = (lane < 16) ? sqT[0]  : (lane < 32) ? sqT[1]  : (lane < 48) ? sqT[2]  : sqT[3];
  atomicAdd(&stats[lane], ssel);
  atomicAdd(&stats[64 + lane], qsel);
}

// ---------------- fixup with inlined BN2 coefficients ----------------
__global__ __launch_bounds__(256) void fixup_kernel(const float* __restrict__ agg, const int* __restrict__ deg,
                                                    const float* __restrict__ stats, float cntInv,
                                                    const float* __restrict__ g, const float* __restrict__ be,
                                                    hfr* __restrict__ xout, int ldx, int N){
  int t = blockIdx.x * 256 + threadIdx.x;
  if (t >= N * 64) return;
  int n = t >> 6, c = t & 63;
  float mu = stats[c] * cntInv;
  float var = stats[64 + c] * cntInv - mu * mu;
  float a = g[c] * rsqrtf(var + EPS);
  float b = be[c] - a * mu;
  float v = 0.f;
  if (deg[n] > 0) v = a * agg[t] + b;
  xout[(size_t)n * ldx + c] = f2h(v);
}

// ---------------- node BN stats over f16 activations ----------------
template<int C>
__global__ __launch_bounds__(256) void statsN_kernel(const hfr* __restrict__ u, float* __restrict__ stats, int N){
  constexpr int RP = 256 / C;
  const int c = threadIdx.x % C, j = threadIdx.x / C;
  float sum = 0.f, sq = 0.f;
  for (int r = blockIdx.x * RP + j; r < N; r += gridDim.x * RP){
    float v = h2f(u[(size_t)r * C + c]);
    sum += v; sq += v * v;
  }
  __shared__ float ls[256], lq[256];
  ls[threadIdx.x] = sum; lq[threadIdx.x] = sq;
  __syncthreads();
  if (threadIdx.x < C){
    float s = 0.f, q = 0.f;
#pragma unroll
    for (int jj = 0; jj < RP; ++jj){ s += ls[jj * C + c]; q += lq[jj * C + c]; }
    atomicAdd(&stats[c], s); atomicAdd(&stats[C + c], q);
  }
}

// ---------------- head: logits + log_softmax ----------------
__global__ __launch_bounds__(256) void head_kernel(const hfr* __restrict__ u2,
                                                   const float* __restrict__ Wo, const float* __restrict__ bo,
                                                   void* __restrict__ out, int N, const int* __restrict__ flag){
  __shared__ float Ws[32 * 24];
  __shared__ float bs[24];
  for (int i = threadIdx.x; i < 32 * 24; i += 256) Ws[i] = Wo[i];
  if (threadIdx.x < 24) bs[threadIdx.x] = bo[threadIdx.x];
  __syncthreads();
  int r = blockIdx.x * 256 + threadIdx.x;
  if (r >= N) return;
  int isf = *flag;
  float l[24];
#pragma unroll
  for (int c = 0; c < 24; ++c) l[c] = bs[c];
  const hfr* up = u2 + (size_t)r * 32;
#pragma unroll
  for (int k = 0; k < 32; ++k){
    float v = h2f(up[k]);
#pragma unroll
    for (int c = 0; c < 24; ++c) l[c] += v * Ws[k * 24 + c];
  }
  float m = l[0];
#pragma unroll
  for (int c = 1; c < 24; ++c) m = fmaxf(m, l[c]);
  float s = 0.f;
#pragma unroll
  for (int c = 0; c < 24; ++c) s += expf(l[c] - m);
  float lse = m + logf(s);
  if (isf){
    float4* op = (float4*)((float*)out + (size_t)r * 24);
#pragma unroll
    for (int i = 0; i < 6; ++i)
      op[i] = make_float4(l[4*i] - lse, l[4*i+1] - lse, l[4*i+2] - lse, l[4*i+3] - lse);
  } else {
    unsigned p[12];
#pragma unroll
    for (int c = 0; c < 24; c += 2) p[c / 2] = pack2bf(l[c] - lse, l[c + 1] - lse);
    uint4* op = (uint4*)((bfr*)out + (size_t)r * 24);
#pragma unroll
    for (int i = 0; i < 3; ++i) op[i] = make_uint4(p[4*i], p[4*i+1], p[4*i+2], p[4*i+3]);
  }
}

// ---------------- host ----------------
// Footprint ~51 MB (ws-safe since round 3). Aliases disjoint in time:
// u_l over P+Q+agg (dead after conv loop); u1/u2 over xcat (dead after lin1).
extern "C" void kernel_launch(void* const* d_in, const int* in_sizes, int n_in,
                              void* d_out, int out_size, void* d_ws, size_t ws_size,
                              hipStream_t stream){
  const int N = in_sizes[0] / 6;
  const int E = in_sizes[31] / 2;
  const int* edge = (const int*)d_in[31];
  const int* src = edge;
  const int* dst = edge + E;

  size_t off = 0; char* basep = (char*)d_ws;
  auto alloc = [&](size_t bytes) -> void* {
    void* p = basep + off;
    off = (off + bytes + 255) & ~(size_t)255;
    return p;
  };
  float* W2   = (float*)alloc(64 * 64 * 4);
  float* b2   = (float*)alloc(64 * 4);
  float* Wm1F = (float*)alloc(256 * 64 * 4);
  float* bm1F = (float*)alloc(64 * 4);
  float* Wm2F = (float*)alloc(64 * 32 * 4);
  float* bm2F = (float*)alloc(32 * 4);
  float* WoF  = (float*)alloc(32 * 24 * 4);
  float* boF  = (float*)alloc(24 * 4);
  float* stE  = (float*)alloc(256 * 4);     // [0:128) BN1, [128:256) BN2
  float* stE2 = stE + 128;
  float* stN  = (float*)alloc(512 * 4);
  int*   flag = (int*)  alloc(4);
  int*   deg  = (int*)  alloc((size_t)N * 4);
  int*   rowo = (int*)  alloc((size_t)(N + 1) * 4);
  int*   cur  = (int*)  alloc((size_t)N * 4);
  int*   ssrc = (int*)  alloc((size_t)E * 4);

  ParamPtrs pp; ParamOfs po;
  int hoff[32]; int total = 0;
  for (int s = 0; s < NPAR; ++s){
    int idx = (s < 30) ? (s + 1) : 0;
    pp.p[s] = d_in[idx];
    po.off[s] = total;
    hoff[idx] = total;
    total += in_sizes[idx];
  }
  po.off[NPAR] = total;
  float* pf = (float*)alloc((size_t)total * 4);

  hfr*   P    = (hfr*)  alloc((size_t)N * 64 * 2);
  hfr*   Qb   = (hfr*)  alloc((size_t)N * 64 * 2);
  float* agg  = (float*)alloc((size_t)N * 64 * 4);
  hfr*   xcat = (hfr*)  alloc((size_t)N * 192 * 2);
  hfr* u_l = (hfr*)P;                 // [N,256] f16 over P+Q+agg
  hfr* u1  = xcat;                    // [N,64]  f16
  hfr* u2  = xcat + (size_t)N * 64;   // [N,32]  f16
  (void)ws_size; (void)n_in; (void)out_size;

  dim3 B(256);
  detect_kernel<<<1, B, 0, stream>>>((const bfr*)d_in[0], 256, flag);
  acvt_batch_kernel<<<cdiv(total, 256), B, 0, stream>>>(pp, po, pf, total, flag);

  hipMemsetAsync(deg, 0, (size_t)N * 4, stream);
  deg_kernel<<<cdiv(E, 256), B, 0, stream>>>(dst, deg, E);
  scan_kernel<<<1, B, 0, stream>>>(deg, rowo, cur, N);
  scatter_kernel<<<cdiv(E, 256), B, 0, stream>>>(src, dst, cur, ssrc, E);

  const int NB = cdiv(N, 256);
  const int GWA = 2048, GWB = 1024;
  const float Einv = 1.f / (float)E;
  for (int k = 0; k < 3; ++k){
    const float *Wa_k, *ba_k, *ga_k, *bea_k, *Wb_k, *bb_k, *gb_k, *beb_k;
    if (k == 0){
      Wa_k = pf + hoff[1]; ba_k = pf + hoff[2]; ga_k = pf + hoff[3]; bea_k = pf + hoff[4];
      Wb_k = pf + hoff[5]; bb_k = pf + hoff[6]; gb_k = pf + hoff[7]; beb_k = pf + hoff[8];
    } else {
      int kk = k - 1;
      Wa_k = pf + hoff[9]  + (size_t)kk * 128 * 64;
      ba_k = pf + hoff[10] + kk * 64;
      ga_k = pf + hoff[11] + kk * 64;
      bea_k= pf + hoff[12] + kk * 64;
      Wb_k = pf + hoff[13] + (size_t)kk * 64 * 64;
      bb_k = pf + hoff[14] + kk * 64;
      gb_k = pf + hoff[15] + kk * 64;
      beb_k= pf + hoff[16] + kk * 64;
    }
    if (k == 0)
      gemmPQ_kernel<true><<<dim3(NB, 2), B, 0, stream>>>(pf + hoff[0], 6, Wa_k, 6, ba_k, P, Qb, N);
    else
      gemmPQ_kernel<false><<<dim3(NB, 2), B, 0, stream>>>(xcat + (size_t)(k - 1) * 64, 192, Wa_k, 64, ba_k, P, Qb, N);
    hipMemsetAsync(stE, 0, 256 * 4, stream);
    passA_kernel<<<GWA, B, 0, stream>>>(P, Qb, ssrc, rowo, stE, N);
    fold_kernel<<<1, B, 0, stream>>>(stE, Einv, ga_k, bea_k, Wb_k, bb_k, W2, b2, 64, 64);
    passBC_kernel<<<GWB, B, 0, stream>>>(P, Qb, ssrc, rowo, W2, b2, agg, stE2, N);
    fixup_kernel<<<cdiv(N * 64, 256), B, 0, stream>>>(agg, deg, stE2, Einv, gb_k, beb_k,
                                                      xcat + (size_t)k * 64, 192, N);
  }

  // node MLP
  gemm_kernel<64, true><<<dim3(NB, 4), B, 0, stream>>>(xcat, 192, pf + hoff[17], 256,
                                                       pf + hoff[18], u_l, 256, N, 192, 1);
  hipMemsetAsync(stN, 0, 512 * 4, stream);
  statsN_kernel<256><<<2048, B, 0, stream>>>(u_l, stN, N);
  fold_kernel<<<1, B, 0, stream>>>(stN, 1.f / (float)N, pf + hoff[19], pf + hoff[20],
                                   pf + hoff[21], pf + hoff[22], Wm1F, bm1F, 256, 64);
  gemm_kernel<64, true><<<dim3(NB, 1), B, 0, stream>>>(u_l, 256, Wm1F, 64, bm1F, u1, 64, N, 256, 1);
  hipMemsetAsync(stN, 0, 128 * 4, stream);
  statsN_kernel<64><<<2048, B, 0, stream>>>(u1, stN, N);
  fold_kernel<<<1, B, 0, stream>>>(stN, 1.f / (float)N, pf + hoff[23], pf + hoff[24],
                                   pf + hoff[25], pf + hoff[26], Wm2F, bm2F, 64, 32);
  gemm_kernel<32, true><<<dim3(NB, 1), B, 0, stream>>>(u1, 64, Wm2F, 32, bm2F, u2, 32, N, 64, 1);
  hipMemsetAsync(stN, 0, 64 * 4, stream);
  statsN_kernel<32><<<2048, B, 0, stream>>>(u2, stN, N);
  fold_kernel<<<1, B, 0, stream>>>(stN, 1.f / (float)N, pf + hoff[27], pf + hoff[28],
                                   pf + hoff[29], pf + hoff[30], WoF, boF, 32, 24);
  head_kernel<<<cdiv(N, 256), B, 0, stream>>>(u2, WoF, boF, d_out, N, flag);
}